// Round 3
// baseline (1016.554 us; speedup 1.0000x reference)
//
#include <hip/hip_runtime.h>

typedef unsigned short u16;
typedef unsigned int   u32;

typedef __bf16 bf16x8 __attribute__((ext_vector_type(8)));
typedef float  f32x4  __attribute__((ext_vector_type(4)));

#define NNODE 4096
#define NEDGE 8192
#define NEG   12288   /* edges incl self-loops */

__device__ __forceinline__ float blo(u32 u){ return __uint_as_float(u<<16); }
__device__ __forceinline__ float bhi(u32 u){ return __uint_as_float(u & 0xffff0000u); }
__device__ __forceinline__ u16 f2b(float f){
  u32 u = __float_as_uint(f);
  u += 0x7fffu + ((u>>16)&1u);
  return (u16)(u>>16);
}
__device__ __forceinline__ void split_bf(float a, u16& hi, u16& lo){
  u32 u = __float_as_uint(a);
  u32 r = u + 0x7fffu + ((u>>16)&1u);
  hi = (u16)(r>>16);
  float h = __uint_as_float(r & 0xffff0000u);
  float l = a - h;
  u32 u2 = __float_as_uint(l);
  lo = (u16)((u2 + 0x7fffu + ((u2>>16)&1u)) >> 16);
}
__device__ __forceinline__ u16 hi_bf(float a){
  u32 u = __float_as_uint(a);
  return (u16)((u + 0x7fffu + ((u>>16)&1u)) >> 16);
}

#define GL2LDS(g,l) __builtin_amdgcn_global_load_lds((const __attribute__((address_space(1))) unsigned int*)(g), (__attribute__((address_space(3))) unsigned int*)(l), 16, 0, 0)

// ---------------- graph prep ----------------
__global__ __launch_bounds__(256) void zero_i(int* p, int n){
  int i = blockIdx.x*256 + threadIdx.x; if (i<n) p[i]=0;
}
__global__ __launch_bounds__(256) void hist_k(const int* __restrict__ ei, int* deg_g, int* deg_t){
  int e = blockIdx.x*256 + threadIdx.x; if (e>=NEG) return;
  int dv = (e<NEDGE) ? ei[NEDGE+e] : e-NEDGE;
  atomicAdd(&deg_g[dv],1);
  if (e<NEDGE) atomicAdd(&deg_t[dv],1);
}
__global__ __launch_bounds__(1024) void scan4096(const int* __restrict__ deg, int* __restrict__ off){
  __shared__ int lds[1024];
  int tid = threadIdx.x;
  int v[4]; int s=0;
  #pragma unroll
  for (int j=0;j<4;j++){ v[j]=deg[tid*4+j]; s+=v[j]; }
  lds[tid]=s; __syncthreads();
  for (int d=1; d<1024; d<<=1){
    int t = (tid>=d) ? lds[tid-d] : 0;
    __syncthreads();
    lds[tid] += t;
    __syncthreads();
  }
  int base = (tid>0) ? lds[tid-1] : 0;
  #pragma unroll
  for (int j=0;j<4;j++){ off[tid*4+j]=base; base+=v[j]; }
  if (tid==1023) off[4096]=base;
}
__global__ __launch_bounds__(256) void scatter_k(const int* __restrict__ ei,
    const int* __restrict__ off_g, int* cur_g, int* csr_g,
    const int* __restrict__ off_t, int* cur_t, int* csr_t){
  int e = blockIdx.x*256 + threadIdx.x; if (e>=NEG) return;
  int s, dv;
  if (e<NEDGE){ s=ei[e]; dv=ei[NEDGE+e]; } else { s=dv=e-NEDGE; }
  int p = atomicAdd(&cur_g[dv],1);
  csr_g[off_g[dv]+p]=s;
  if (e<NEDGE){ int p2 = atomicAdd(&cur_t[dv],1); csr_t[off_t[dv]+p2]=s; }
}
__global__ __launch_bounds__(256) void mkdis(const int* __restrict__ deg, float* dis){
  int i = blockIdx.x*256 + threadIdx.x; if (i>=NNODE) return;
  int d = deg[i]; dis[i] = d>0 ? rsqrtf((float)d) : 0.f;
}
// xpad fp32 [n][80] + xph bf16-hi [n][96]
__global__ __launch_bounds__(128) void pad_x(const float* __restrict__ x, float* __restrict__ xp,
                                             u16* __restrict__ xh){
  int n = blockIdx.x, c = threadIdx.x;
  if (c<96){
    float v = (c<78) ? x[(size_t)n*78+c] : 0.f;
    if (c<80) xp[(size_t)n*80+c] = v;
    xh[(size_t)n*96+c] = hi_bf(v);
  }
}
// W1r[(h*80+k), c] = g1_w[k, h*2048+c], zero-padded k>=78
__global__ __launch_bounds__(256) void repack_w1(const float* __restrict__ g1w, float* __restrict__ w1r){
  int i = blockIdx.x*256 + threadIdx.x;   // 640*2048
  int kk = i >> 11, c = i & 2047;
  int h = kk/80, k2 = kk - h*80;
  w1r[i] = (k2<78) ? g1w[(size_t)k2*16384 + h*2048 + c] : 0.f;
}

// ---------------- transpose + bf16(hi): W[K,Ntot] cols [n0,n0+Nw) -> hi [Nw,Kp] ----------------
__global__ __launch_bounds__(256) void tpd(const float* __restrict__ in, int Ntot, int n0,
    int K, int Kp, u16* __restrict__ outh){
  __shared__ float t[32][33];
  int bx = blockIdx.x*32;   // n in window
  int by = blockIdx.y*32;   // k
  int tx = threadIdx.x & 31, ty = threadIdx.x >> 5;
  for (int i=ty;i<32;i+=8){
    int kk=by+i;
    t[i][tx] = (kk<K) ? in[(size_t)kk*Ntot + n0 + bx + tx] : 0.f;
  }
  __syncthreads();
  for (int i=ty;i<32;i+=8){
    int nn=bx+i, kk=by+tx;
    if (kk<Kp) outh[(size_t)nn*Kp+kk] = hi_bf(t[tx][i]);
  }
}

// ---------------- attention-table pack: [16][Kp] rows 0..7 = ws heads, 8..15 = wd ----------------
__global__ __launch_bounds__(256) void mk_wsT(const float* __restrict__ wsv, const float* __restrict__ wdv,
    u16* __restrict__ th, u16* __restrict__ tl, int Kp){
  int i = blockIdx.x*256 + threadIdx.x;   // over 16*Kp
  if (i >= 16*Kp) return;
  int r = i / Kp, k = i - r*Kp;
  float v = (r<8) ? wsv[k*8+r] : wdv[k*8+(r-8)];
  u16 h,l; split_bf(v,h,l);
  th[i]=h; tl[i]=l;
}

// LDS bank-conflict-free swizzle for [16-row][4x16B] groups staged via global_load_lds:
//   write: lane L fetches logical 16B-col jl = ((L&3) - (L>>3)) & 3  (row = L>>2)
//   read : row rig, logical col q lives at physical slot jp = (q + (rig>>1)) & 3

// ---------------- K-split logits GEMM: alsd[4096][16] += (Ah+Al) * (Bh+Bl)^T ----------------
template<int KS>
__global__ __launch_bounds__(256,4) void alk_mm(
    const u16* __restrict__ Ah, const u16* __restrict__ Al, int lda,
    const u16* __restrict__ Bh, const u16* __restrict__ Bl,
    float* __restrict__ alsd, int K)
{
  __shared__ __align__(16) u16 Ash[128*32], Asl[128*32], Bsh[16*32], Bsl[16*32];
  int tid = threadIdx.x, lane = tid & 63, wave = tid >> 6;
  int bm = blockIdx.y*128;
  int kb = blockIdx.x*(K/KS), ke = kb + K/KS;
  int m16 = lane & 15, quad = lane >> 4;
  int srow = lane >> 2;
  int skk = (((lane & 3) - (srow >> 1)) & 3) * 8;   // swizzled logical col
  int kq  = (((quad + (m16 >> 1)) & 3)) * 8;        // swizzled read slot
  f32x4 acc[2] = {};
  for (int k0=kb; k0<ke; k0+=32){
    __syncthreads();
    #pragma unroll
    for (int t=0;t<2;t++){
      int g = wave + t*4; int row = g*16 + srow;
      GL2LDS(Ah + (size_t)(bm+row)*lda + k0 + skk, &Ash[g*512]);
      GL2LDS(Al + (size_t)(bm+row)*lda + k0 + skk, &Asl[g*512]);
    }
    if (wave==0) GL2LDS(Bh + (size_t)srow*lda + k0 + skk, &Bsh[0]);
    if (wave==1) GL2LDS(Bl + (size_t)srow*lda + k0 + skk, &Bsl[0]);
    __syncthreads();
    bf16x8 bh = *(const bf16x8*)&Bsh[m16*32+kq];
    bf16x8 bl = *(const bf16x8*)&Bsl[m16*32+kq];
    #pragma unroll
    for (int i=0;i<2;i++){
      bf16x8 ah = *(const bf16x8*)&Ash[(wave*32+i*16+m16)*32+kq];
      bf16x8 al = *(const bf16x8*)&Asl[(wave*32+i*16+m16)*32+kq];
      acc[i] = __builtin_amdgcn_mfma_f32_16x16x32_bf16(ah, bh, acc[i],0,0,0);
      acc[i] = __builtin_amdgcn_mfma_f32_16x16x32_bf16(al, bh, acc[i],0,0,0);
      acc[i] = __builtin_amdgcn_mfma_f32_16x16x32_bf16(ah, bl, acc[i],0,0,0);
    }
  }
  #pragma unroll
  for (int i=0;i<2;i++){
    int row0 = bm + wave*32 + i*16 + quad*4;
    #pragma unroll
    for (int r=0;r<4;r++)
      atomicAdd(&alsd[(size_t)(row0+r)*16 + m16], acc[i][r]);
  }
}

// ---------------- MFMA GEMM (m97 staging + swizzle): C = (Ah[+Al]) * Bh^T ----------------
// EPI: 0 plain CT store, 1 +bias CT store, 5 relu(scale*acc+bias) -> split hi/lo only
#define BM 128
#define BN 128
template<int EPI, int SA, typename CT>
__global__ __launch_bounds__(256,4) void mgemm(
    const u16* __restrict__ Ah, const u16* __restrict__ Al, int lda,
    const u16* __restrict__ Bh, int ldb,
    CT* __restrict__ C, int ldc, int K,
    const float* __restrict__ bias, float scale,
    u16* __restrict__ Chi, u16* __restrict__ Clo)
{
  __shared__ __align__(16) u16 Ash[128*32];
  __shared__ __align__(16) u16 Bsh[128*32];
  __shared__ __align__(16) u16 Asl[SA?128*32:16];
  int tid = threadIdx.x;
  int bm = blockIdx.y*BM, bn = blockIdx.x*BN;
  int lane = tid & 63, wave = tid >> 6;
  int wr = (wave>>1)*64, wc = (wave&1)*64;
  int m16 = lane & 15, quad = lane >> 4;
  int srow = lane >> 2;
  int skk = (((lane & 3) - (srow >> 1)) & 3) * 8;   // swizzled fetch col
  int kq  = (((quad + (m16 >> 1)) & 3)) * 8;        // swizzled read slot

  f32x4 acc[4][4] = {};
  for (int k0=0; k0<K; k0+=32){
    __syncthreads();
    #pragma unroll
    for (int t=0;t<2;t++){
      int g = wave + t*4;
      int row = g*16 + srow;
      GL2LDS(Ah + (size_t)(bm+row)*lda + k0 + skk, &Ash[g*512]);
      if (SA) GL2LDS(Al + (size_t)(bm+row)*lda + k0 + skk, &Asl[g*512]);
      GL2LDS(Bh + (size_t)(bn+row)*ldb + k0 + skk, &Bsh[g*512]);
    }
    __syncthreads();
    bf16x8 ah[4], al_[4], bh_[4];
    #pragma unroll
    for (int i=0;i<4;i++){
      ah[i]  = *(const bf16x8*)&Ash[(wr+i*16+m16)*32 + kq];
      if (SA) al_[i] = *(const bf16x8*)&Asl[(wr+i*16+m16)*32 + kq];
    }
    #pragma unroll
    for (int j=0;j<4;j++)
      bh_[j] = *(const bf16x8*)&Bsh[(wc+j*16+m16)*32 + kq];
    #pragma unroll
    for (int i=0;i<4;i++)
      #pragma unroll
      for (int j=0;j<4;j++){
        acc[i][j] = __builtin_amdgcn_mfma_f32_16x16x32_bf16(ah[i], bh_[j], acc[i][j], 0,0,0);
        if (SA) acc[i][j] = __builtin_amdgcn_mfma_f32_16x16x32_bf16(al_[i], bh_[j], acc[i][j], 0,0,0);
      }
  }
  #pragma unroll
  for (int i=0;i<4;i++){
    int row0 = bm + wr + i*16 + quad*4;
    #pragma unroll
    for (int j=0;j<4;j++){
      int col = bn + wc + j*16 + m16;
      float bv = (EPI==1||EPI==5) ? bias[col] : 0.f;
      #pragma unroll
      for (int r=0;r<4;r++){
        float v = acc[i][j][r];
        if constexpr (EPI==5){
          v = fmaxf(v*scale + bv, 0.f);
          size_t idx = (size_t)(row0+r)*ldc + col;
          u16 h_, l_; split_bf(v, h_, l_);
          Chi[idx]=h_; Clo[idx]=l_;
        } else {
          if (EPI==1) v += bv;
          size_t idx = (size_t)(row0+r)*ldc + col;
          if constexpr (sizeof(CT)==2) C[idx] = (CT)f2b(v);
          else C[idx] = (CT)v;
        }
      }
    }
  }
}

// ================= 256x256 / BK=64 / 8-wave 8-phase READ-AHEAD GEMM =================
// C[m][n] = sum_k A[m][k]*B[n][k], all bf16(hi), C bf16.  M,N mult of 256, K mult of 128.
// LDS swizzle: phys_chunk = logical_chunk ^ (row&7) (conflict-free, verified r2: 0 conflicts).
// READ-AHEAD pipeline: every MFMA's operands are ds_read 1-2 phases earlier into
// ping-pong fragment sets (aA/aB for A-halves, b0_/b1_ for B-halves), so the
// compiler's auto lgkmcnt before each MFMA is COUNTED (fresh reads stay in flight).
// Per phase: {4-or-8 ds_reads (for ph+1) | 2 staging loads | sched_barrier | barrier |
//             setprio(1) 16xMFMA setprio(0) | vmcnt(8) | barrier}.
// End-of-phase vmcnt(8) (queue depth 10 = 5 stage-slots x 2) forces the stage from
// 5 phases back to land, and the following barrier publishes it cross-wave before
// the region is ds_read next phase.  Stage slots (2 loads each):
//   ph1:A1'(t3prev) ph2:A0(t2) ph3:B0(t2) ph4:B1(t2) ph5:A1(t2)
//   ph6:A0'(t3) ph7:B0'(t3) ph8:B1'(t3)
// Reads: ph1:B1->b1  ph2:A1->aB  ph3:A0'->aA ph4:B0'->b1 ph5:B1'->b0 ph6:A1'->aB
//   ph7:A0''->aA ph8:B0''->b0   (A0,B0 pre-read in prologue)
// MFMA quadrants (same K-accum order as r2 => bitwise-identical C):
//   ph1:(0,0)aA.b0 ph2:(0,1)aA.b1 ph3:(1,1)aB.b1 ph4:(1,0)aB.b0
//   ph5:(0,0)aA.b1 ph6:(0,1)aA.b0 ph7:(1,1)aB.b0 ph8:(1,0)aB.b1
__device__ __forceinline__ void stA8(const u16* __restrict__ A, int lda, u16* dst,
                                     int bm, int kt, int h, int w, int lane){
  int q = ((lane&7) ^ (lane>>3)) * 8;        // logical chunk for this lane's phys slot
  #pragma unroll
  for (int t=0;t<2;t++){
    int rbase = t*128 + h*64 + w*8;          // wave-uniform, multiple of 8
    int rl = rbase + (lane>>3);
    GL2LDS(A + (size_t)(bm+rl)*lda + kt*64 + q, dst + rbase*64);
  }
}
__device__ __forceinline__ void stB8(const u16* __restrict__ B, int ldb, u16* dst,
                                     int bn, int kt, int nh, int w, int lane){
  int q = ((lane&7) ^ (lane>>3)) * 8;
  #pragma unroll
  for (int t=0;t<2;t++){
    int rbase = (w>>1)*64 + nh*32 + (w&1)*16 + t*8;  // wave-uniform, multiple of 8
    int rl = rbase + (lane>>3);
    GL2LDS(B + (size_t)(bn+rl)*ldb + kt*64 + q, dst + rbase*64);
  }
}
#define LDX8(BUF, ROW, KS) \
  (*(const bf16x8*)&(BUF)[(ROW)*64 + ((((KS)*4 + quad) ^ (m16 & 7)))*8])
#define RDA8(BUF, MH, AA) \
  _Pragma("unroll") for (int mi=0;mi<4;mi++){ \
    AA[mi][0] = LDX8(BUF, wr*128 + ((MH)*4+mi)*16 + m16, 0); \
    AA[mi][1] = LDX8(BUF, wr*128 + ((MH)*4+mi)*16 + m16, 1); }
#define RDB8(BUF, NH, BB) \
  _Pragma("unroll") for (int nj=0;nj<2;nj++){ \
    BB[nj][0] = LDX8(BUF, wc*64 + ((NH)*2+nj)*16 + m16, 0); \
    BB[nj][1] = LDX8(BUF, wc*64 + ((NH)*2+nj)*16 + m16, 1); }
#define MMQ8(MH, NH, AA, BB) \
  _Pragma("unroll") for (int mi=0;mi<4;mi++) \
    _Pragma("unroll") for (int nj=0;nj<2;nj++){ \
      acc[(MH)*4+mi][(NH)*2+nj] = __builtin_amdgcn_mfma_f32_16x16x32_bf16(AA[mi][0], BB[nj][0], acc[(MH)*4+mi][(NH)*2+nj],0,0,0); \
      acc[(MH)*4+mi][(NH)*2+nj] = __builtin_amdgcn_mfma_f32_16x16x32_bf16(AA[mi][1], BB[nj][1], acc[(MH)*4+mi][(NH)*2+nj],0,0,0); }
#define BAR   __builtin_amdgcn_s_barrier()
#define SBAR  __builtin_amdgcn_sched_barrier(0)
#define VM8   asm volatile("s_waitcnt vmcnt(8)" ::: "memory")
#define MMPH(MH,NH,AA,BB) \
  SBAR; BAR; \
  __builtin_amdgcn_s_setprio(1); MMQ8(MH,NH,AA,BB); __builtin_amdgcn_s_setprio(0); \
  VM8; BAR;

__global__ __launch_bounds__(512,2) void mgemm8(
    const u16* __restrict__ A, int lda,
    const u16* __restrict__ B, int ldb,
    u16* __restrict__ C, int ldc, int K, int nbx)
{
  __shared__ __align__(16) u16 As0[16384], As1[16384], Bs0[16384], Bs1[16384];
  int tid = threadIdx.x, lane = tid & 63, w = tid >> 6;
  int m16 = lane & 15, quad = lane >> 4;
  int wr = w >> 2, wc = w & 3;
  // bijective XCD swizzle (gridDim.x % 8 == 0)
  int nwg = (int)gridDim.x, bid = (int)blockIdx.x;
  int wg = (bid & 7)*(nwg>>3) + (bid>>3);
  int by = wg / nbx, bx = wg - by*nbx;
  int bm = by*256, bn = bx*256;
  int NT = K >> 6, NP = NT >> 1;
  f32x4 acc[8][4] = {};
  bf16x8 aA[4][2], aB[4][2], b0_[2][2], b1_[2][2];
  // prologue: tile0 full (A0,B0,B1,A1) + tile1 partial (A0',B0',B1') = 14 loads/wave
  stA8(A,lda,As0,bm,0,0,w,lane);
  stB8(B,ldb,Bs0,bn,0,0,w,lane);
  stB8(B,ldb,Bs0,bn,0,1,w,lane);
  stA8(A,lda,As0,bm,0,1,w,lane);
  stA8(A,lda,As1,bm,1,0,w,lane);
  stB8(B,ldb,Bs1,bn,1,0,w,lane);
  stB8(B,ldb,Bs1,bn,1,1,w,lane);
  VM8;                                  // forces tile0 A0,B0,B1 landed (queue 14 -> 8)
  BAR;                                  // publish cross-wave
  RDA8(As0,0,aA); RDB8(Bs0,0,b0_);      // pre-read ph1 operands
  for (int i=0;i<NP;i++){
    int t2 = 2*i+2; if (t2>NT-1) t2=NT-1;   // clamped garbage-stage on last iter
    int t3 = 2*i+3; if (t3>NT-1) t3=NT-1;
    int t3p = 2*i+1;
    // ---- ph1: MFMA (0,0) aA.b0 ----
    RDB8(Bs0,1,b1_);
    stA8(A,lda,As1,bm,t3p,1,w,lane);
    MMPH(0,0,aA,b0_);
    // ---- ph2: MFMA (0,1) aA.b1 ----
    RDA8(As0,1,aB);
    stA8(A,lda,As0,bm,t2,0,w,lane);
    MMPH(0,1,aA,b1_);
    // ---- ph3: MFMA (1,1) aB.b1 ----
    RDA8(As1,0,aA);
    stB8(B,ldb,Bs0,bn,t2,0,w,lane);
    MMPH(1,1,aB,b1_);
    // ---- ph4: MFMA (1,0) aB.b0 ----
    RDB8(Bs1,0,b1_);
    stB8(B,ldb,Bs0,bn,t2,1,w,lane);
    MMPH(1,0,aB,b0_);
    // ---- ph5: MFMA (0,0)' aA.b1(=B0') ----
    RDB8(Bs1,1,b0_);
    stA8(A,lda,As0,bm,t2,1,w,lane);
    MMPH(0,0,aA,b1_);
    // ---- ph6: MFMA (0,1)' aA.b0(=B1') ----
    RDA8(As1,1,aB);
    stA8(A,lda,As1,bm,t3,0,w,lane);
    MMPH(0,1,aA,b0_);
    // ---- ph7: MFMA (1,1)' aB.b0(=B1') ----
    RDA8(As0,0,aA);
    stB8(B,ldb,Bs1,bn,t3,0,w,lane);
    MMPH(1,1,aB,b0_);
    // ---- ph8: MFMA (1,0)' aB.b1(=B0') ----
    RDB8(Bs0,0,b0_);
    stB8(B,ldb,Bs1,bn,t3,1,w,lane);
    MMPH(1,0,aB,b1_);
  }
  asm volatile("s_waitcnt vmcnt(0)" ::: "memory");    // drain garbage stages
  #pragma unroll
  for (int mi=0;mi<8;mi++){
    int row0 = bm + wr*128 + mi*16 + quad*4;
    #pragma unroll
    for (int nj=0;nj<4;nj++){
      int col = bn + wc*64 + nj*16 + m16;
      #pragma unroll
      for (int r=0;r<4;r++)
        C[(size_t)(row0+r)*ldc + col] = f2b(acc[mi][nj][r]);
    }
  }
}

// ---------------- GAT attention-vector precompute ----------------
__global__ __launch_bounds__(256) void wsvec(const float* __restrict__ W,
    const float* __restrict__ as_, const float* __restrict__ ad_,
    float* __restrict__ ws, float* __restrict__ wd,
    int Kreal, int H, int C)
{
  int wv = blockIdx.x*4 + (threadIdx.x>>6);
  int lane = threadIdx.x & 63;
  int k = wv / H, h = wv - k*H;
  float ps=0.f, pd=0.f;
  if (k < Kreal){
    const float* wr = W + (size_t)k*((size_t)H*C) + (size_t)h*C;
    const float* ar = as_ + (size_t)h*C;
    const float* dr = ad_ + (size_t)h*C;
    for (int c=lane;c<C;c+=64){ float w=wr[c]; ps += w*ar[c]; pd += w*dr[c]; }
  }
  #pragma unroll
  for (int o=32;o;o>>=1){ ps += __shfl_down(ps,o); pd += __shfl_down(pd,o); }
  if (lane==0){ ws[k*H+h]=ps; wd[k*H+h]=pd; }
}
// GAT1 logits (Kp=80), writes alsd[n][16] = [als(8) | ald(8)]
__global__ __launch_bounds__(256) void alk(const float* __restrict__ X,
    const float* __restrict__ ws, const float* __restrict__ wd,
    float* __restrict__ alsd, int Kp)
{
  int n = blockIdx.x, tid = threadIdx.x;
  int hh = tid>>5, l32 = tid&31;
  const float* xr = X + (size_t)n*Kp;
  float ps=0.f, pd=0.f;
  for (int k=l32;k<Kp;k+=32){
    float xv = xr[k];
    ps += xv*ws[k*8+hh];
    pd += xv*wd[k*8+hh];
  }
  #pragma unroll
  for (int o=16;o;o>>=1){ ps += __shfl_down(ps,o,32); pd += __shfl_down(pd,o,32); }
  if (l32==0){ alsd[n*16+hh]=ps; alsd[n*16+8+hh]=pd; }
}

// ---------------- GAT1 aggregate-first gather (emits hi/lo) ----------------
__global__ __launch_bounds__(256) void gat1_gather(
    const float* __restrict__ xpad, const float* __restrict__ alsd,
    const int* __restrict__ off, const int* __restrict__ csr,
    u16* __restrict__ y1h, u16* __restrict__ y1l)
{
  int d = blockIdx.x, tid = threadIdx.x;
  int hh = tid>>5, l32 = tid&31;
  int e0 = off[d], e1 = off[d+1];
  __shared__ float mh[8], lih[8], adh[8];
  __shared__ float wl[32][8];
  __shared__ int sl[32];
  if (tid < 8){
    float ad = alsd[d*16+8+tid]; adh[tid]=ad;
    float m=-1e30f, l=0.f;
    for (int e=e0;e<e1;++e){
      float xv = alsd[csr[e]*16+tid] + ad;
      xv = xv>0.f?xv:0.2f*xv;
      if (xv>m){ l = l*__expf(m-xv)+1.f; m=xv; } else l += __expf(xv-m);
    }
    mh[tid]=m; lih[tid]=1.f/l;
  }
  __syncthreads();
  float acc0=0.f, acc1=0.f, acc2v=0.f;
  for (int cb=e0; cb<e1; cb+=32){
    int ce = min(32, e1-cb);
    if (tid < ce*8){
      int j = tid>>3, h2 = tid&7;
      int s = csr[cb+j];
      if (h2==0) sl[j]=s;
      float xv = alsd[s*16+h2] + adh[h2];
      xv = xv>0.f?xv:0.2f*xv;
      wl[j][h2] = __expf(xv-mh[h2])*lih[h2];
    }
    __syncthreads();
    for (int j=0;j<ce;++j){
      float w = wl[j][hh];
      const float* xr = xpad + (size_t)sl[j]*80;
      acc0 += w*xr[l32];
      acc1 += w*xr[l32+32];
      if (l32 < 16) acc2v += w*xr[l32+64];
    }
    __syncthreads();
  }
  size_t base = (size_t)d*640 + hh*80;
  u16 h_, l_;
  split_bf(acc0, h_, l_); y1h[base+l32]=h_;    y1l[base+l32]=l_;
  split_bf(acc1, h_, l_); y1h[base+l32+32]=h_; y1l[base+l32+32]=l_;
  if (l32<16){ split_bf(acc2v, h_, l_); y1h[base+l32+64]=h_; y1l[base+l32+64]=l_; }
}

// ---------------- all-head chunk aggregation (bf16 h, alsd layout) ----------------
template<int HPC, int C>
__global__ __launch_bounds__(256) void gat_aggN(
    const u16* __restrict__ h, const float* __restrict__ alsd,
    const int* __restrict__ off, const int* __restrict__ csr,
    float* __restrict__ accum, int head0)
{
  constexpr int V = C/256;
  int d = blockIdx.x, tid = threadIdx.x;
  int e0=off[d], e1=off[d+1];
  __shared__ float mh[HPC], lih[HPC], adh[HPC];
  __shared__ float wl[32][HPC];
  __shared__ int sl[32];
  if (tid < HPC){
    float ad = alsd[d*16 + 8 + head0 + tid]; adh[tid]=ad;
    float m=-1e30f,l=0.f;
    for (int e=e0;e<e1;++e){
      float xv = alsd[csr[e]*16 + head0 + tid]+ad;
      xv = xv>0.f?xv:0.2f*xv;
      if (xv>m){ l=l*__expf(m-xv)+1.f; m=xv; } else l+=__expf(xv-m);
    }
    mh[tid]=m; lih[tid]=1.f/l;
  }
  __syncthreads();
  float acc[HPC][V];
  #pragma unroll
  for (int a=0;a<HPC;a++)
    #pragma unroll
    for (int v=0;v<V;v++) acc[a][v]=0.f;
  int c0 = tid*V;
  for (int cb=e0;cb<e1;cb+=32){
    int ce = min(32, e1-cb);
    if (tid < ce*HPC){
      int j = tid/HPC, h2 = tid - j*HPC;
      int s = csr[cb+j];
      if (h2==0) sl[j]=s;
      float xv = alsd[s*16 + head0 + h2] + adh[h2];
      xv = xv>0.f?xv:0.2f*xv;
      wl[j][h2] = __expf(xv-mh[h2])*lih[h2];
    }
    __syncthreads();
    for (int j=0;j<ce;++j){
      const u16* hr = h + (size_t)sl[j]*(HPC*C);
      #pragma unroll
      for (int a=0;a<HPC;a++){
        float w = wl[j][a];
        if constexpr (V==4){
          uint2 u = *(const uint2*)(hr + a*C + c0);
          acc[a][0] += w*blo(u.x); acc[a][1] += w*bhi(u.x);
          acc[a][2] += w*blo(u.y); acc[a][3] += w*bhi(u.y);
        } else {
          u32 u = *(const u32*)(hr + a*C + c0);
          acc[a][0] += w*blo(u); acc[a][1] += w*bhi(u);
        }
      }
    }
    __syncthreads();
  }
  float* ar = accum + (size_t)d*C + c0;
  #pragma unroll
  for (int v=0;v<V;v++){
    float s2 = 0.f;
    #pragma unroll
    for (int a=0;a<HPC;a++) s2 += acc[a][v];
    ar[v] += s2;
  }
}
// x3 = relu(acc/8 + b[c])  (fp32 out, GAT3)
__global__ __launch_bounds__(256) void finishx(const float* __restrict__ accum,
    const float* __restrict__ bias, float* __restrict__ xo, int Cmask){
  int i = blockIdx.x*256 + threadIdx.x;
  int c = i & Cmask;
  xo[i] = fmaxf(accum[i]*0.125f + bias[c], 0.f);
}
// x2 = relu(acc/8 + b[c]) -> hi/lo only (GAT2)
__global__ __launch_bounds__(256) void finishx2(const float* __restrict__ accum,
    const float* __restrict__ bias,
    u16* __restrict__ xh, u16* __restrict__ xl, int Cmask){
  int i = blockIdx.x*256 + threadIdx.x;
  int c = i & Cmask;
  float v = fmaxf(accum[i]*0.125f + bias[c], 0.f);
  u16 h_, l_; split_bf(v, h_, l_);
  xh[i]=h_; xl[i]=l_;
}

// ---------------- pooled GCN aggregation ----------------
__global__ __launch_bounds__(256) void pool_gcn(const float* __restrict__ x3,
    const float* __restrict__ dis, const int* __restrict__ off, const int* __restrict__ csr,
    float* __restrict__ z)
{
  int g = blockIdx.x, tid = threadIdx.x;
  int c0 = tid*2;
  float a0=0.f, a1=0.f;
  for (int dd=0; dd<32; ++dd){
    int d = g*32+dd;
    int e0=off[d], e1=off[d+1];
    float b0=0.f, b1=0.f;
    for (int e=e0;e<e1;++e){
      int s = csr[e]; float ds = dis[s];
      const float* xr = x3 + (size_t)s*512 + c0;
      b0 += ds*xr[0]; b1 += ds*xr[1];
    }
    float dw = dis[d];
    a0 += dw*b0; a1 += dw*b1;
  }
  z[(size_t)g*512+c0]   = a0*(1.f/32.f);
  z[(size_t)g*512+c0+1] = a1*(1.f/32.f);
}

// ---------------- TransformerConv aggregation (bf16 qkvs, logit-cache) ----------------
__global__ __launch_bounds__(256) void tr_agg(
  const u16* __restrict__ qkvs, const int* __restrict__ off, const int* __restrict__ csr,
  float* __restrict__ xt)
{
  int d = blockIdx.x, tid = threadIdx.x;
  int wv = tid>>6, lane = tid&63;
  int e0=off[d], e1=off[d+1];
  __shared__ float osum[4][512];
  __shared__ float sp[4][64];
  float qf[8];
  { uint4 u = *(const uint4*)(qkvs + (size_t)d*6656 + wv*512 + lane*8);
    qf[0]=blo(u.x); qf[1]=bhi(u.x); qf[2]=blo(u.y); qf[3]=bhi(u.y);
    qf[4]=blo(u.z); qf[5]=bhi(u.z); qf[6]=blo(u.w); qf[7]=bhi(u.w); }
  const float scale = 0.04419417382415922f; // 1/sqrt(512)
  float m=-1e30f,l=0.f;
  for (int e=e0;e<e1;++e){
    int s = csr[e];
    uint4 u = *(const uint4*)(qkvs + (size_t)s*6656 + 2048 + wv*512 + lane*8);
    float p = qf[0]*blo(u.x)+qf[1]*bhi(u.x)+qf[2]*blo(u.y)+qf[3]*bhi(u.y)
            + qf[4]*blo(u.z)+qf[5]*bhi(u.z)+qf[6]*blo(u.w)+qf[7]*bhi(u.w);
    #pragma unroll
    for (int o=32;o;o>>=1) p += __shfl_xor(p,o);
    p *= scale;
    int idx = e-e0;
    if (lane==0 && idx<64) sp[wv][idx]=p;
    if (p>m){ l=l*__expf(m-p)+1.f; m=p; } else l+=__expf(p-m);
  }
  float li = (e1>e0)?1.f/l:0.f;
  float acc[8]={0.f,0.f,0.f,0.f,0.f,0.f,0.f,0.f};
  for (int e=e0;e<e1;++e){
    int s = csr[e];
    int idx = e-e0;
    float p;
    if (idx<64) p = sp[wv][idx];
    else {
      uint4 u = *(const uint4*)(qkvs + (size_t)s*6656 + 2048 + wv*512 + lane*8);
      p = qf[0]*blo(u.x)+qf[1]*bhi(u.x)+qf[2]*blo(u.y)+qf[3]*bhi(u.y)
        + qf[4]*blo(u.z)+qf[5]*bhi(u.z)+qf[6]*blo(u.w)+qf[7]*bhi(u.w);
      #pragma unroll
      for (int o=32;o;o>>=1) p += __shfl_xor(p,o);
      p *= scale;
    }
    float w = __expf(p - m)*li;
    uint4 u = *(const uint4*)(qkvs + (size_t)s*6656 + 4096 + wv*512 + lane*8);
    acc[0]+=w*blo(u.x); acc[1]+=w*bhi(u.x); acc[2]+=w*blo(u.y); acc[3]+=w*bhi(u.y);
    acc[4]+=w*blo(u.z); acc[5]+=w*bhi(u.z); acc[6]+=w*blo(u.w); acc[7]+=w*bhi(u.w);
  }
  #pragma unroll
  for (int j=0;j<8;j++) osum[wv][lane*8+j]=acc[j];
  __syncthreads();
  for (int c=tid;c<512;c+=256){
    u16 sk = qkvs[(size_t)d*6656 + 6144 + c];
    float o = (osum[0][c]+osum[1][c]+osum[2][c]+osum[3][c])*0.25f + blo((u32)sk);
    xt[(size_t)d*512+c] = fmaxf(o,0.f);
  }
}

// ---------------- bias concat for qkv GEMM ----------------
__global__ __launch_bounds__(256) void catb(const float* __restrict__ bq, const float* __restrict__ bk,
    const float* __restrict__ bv, const float* __restrict__ bs, float* __restrict__ o){
  int i = blockIdx.x*256 + threadIdx.x; if (i>=6656) return;
  float v;
  if (i<2048) v=bq[i]; else if (i<4096) v=bk[i-2048];
  else if (i<6144) v=bv[i-4096]; else v=bs[i-6144];
  o[i]=v;
}

// ---------------- fused head (bf16 [N,K] weights) ----------------
__device__ __forceinline__ float dotb(const u16* __restrict__ w, const float* __restrict__ s,
                                      int k0, int k1){
  float acc=0.f;
  #pragma unroll 4
  for (int k=k0;k<k1;k+=8){
    uint4 u = *(const uint4*)(w+k);
    float4 s0 = *(const float4*)(s+k);
    float4 s1 = *(const float4*)(s+k+4);
    acc += blo(u.x)*s0.x + bhi(u.x)*s0.y + blo(u.y)*s0.z + bhi(u.y)*s0.w
         + blo(u.z)*s1.x + bhi(u.z)*s1.y + blo(u.w)*s1.z + bhi(u.w)*s1.w;
  }
  return acc;
}
__global__ __launch_bounds__(256) void head_k(
  const float* __restrict__ z, const float* __restrict__ xt, const float* __restrict__ fp,
  const u16* __restrict__ gcnT, const float* __restrict__ gcn_b,
  const u16* __restrict__ fc1T, const float* __restrict__ fc1_b,
  const u16* __restrict__ fc2T, const float* __restrict__ fc2_b,
  const u16* __restrict__ b1T, const float* __restrict__ b1_b,
  const u16* __restrict__ b2T, const float* __restrict__ b2_b,
  const u16* __restrict__ b3T, const float* __restrict__ b3_b,
  const float* __restrict__ b4_w, const float* __restrict__ b4_b,
  float* __restrict__ out)
{
  int g = blockIdx.x, tid = threadIdx.x;
  __shared__ __align__(16) float xc[1024];
  __shared__ __align__(16) float sa[1504];
  __shared__ __align__(16) float sb[256];
  __shared__ __align__(16) float scm[256];
  for (int c=tid;c<512;c+=256) sa[c] = z[(size_t)g*512+c];
  __syncthreads();
  float vgcn = gcn_b[tid] + dotb(gcnT + (size_t)tid*512, sa, 0, 512);
  for (int c=tid;c<512;c+=256){
    float s=0.f;
    for (int i=0;i<32;i++) s += xt[(size_t)(g*32+i)*512 + c];
    xc[256+c] = s*(1.f/32.f);
  }
  xc[tid] = vgcn;
  __syncthreads();
  for (int c=tid;c<1496;c+=256) sa[c] = (c<1489) ? fp[(size_t)g*1489+c] : 0.f;
  __syncthreads();
  { int n = tid & 127, half = tid >> 7;
    sb[tid] = dotb(fc1T + (size_t)n*1496, sa, half?752:0, half?1496:752); }
  __syncthreads();
  if (tid<128) scm[tid] = fmaxf(sb[tid]+sb[tid+128]+fc1_b[tid], 0.f);
  __syncthreads();
  xc[768+tid] = fmaxf(fc2_b[tid] + dotb(fc2T + (size_t)tid*128, scm, 0, 128), 0.f);
  __syncthreads();
  sa[tid] = fmaxf(b1_b[tid] + dotb(b1T + (size_t)tid*1024, xc, 0, 1024), 0.f);
  __syncthreads();
  { int n = tid & 127, half = tid >> 7;
    sb[tid] = dotb(b2T + (size_t)n*256, sa, half*128, half*128+128); }
  __syncthreads();
  if (tid<128) scm[tid] = fmaxf(sb[tid]+sb[tid+128]+b2_b[tid], 0.f);
  __syncthreads();
  { int n = tid & 63, part = tid >> 6;
    sb[tid] = dotb(b3T + (size_t)n*128, scm, part*32, part*32+32); }
  __syncthreads();
  if (tid<64) sa[tid] = fmaxf(sb[tid]+sb[tid+64]+sb[tid+128]+sb[tid+192]+b3_b[tid], 0.f);
  __syncthreads();
  if (tid<64){
    float p = sa[tid]*b4_w[tid];
    #pragma unroll
    for (int o=32;o;o>>=1) p += __shfl_down(p,o);
    if (tid==0) out[g] = 1.f/(1.f+__expf(-(p + b4_b[0])));
  }
}

extern "C" void kernel_launch(void* const* d_in, const int* in_sizes, int n_in,
                              void* d_out, int out_size, void* d_ws, size_t ws_size,
                              hipStream_t stream)
{
  (void)in_sizes; (void)n_in; (void)out_size; (void)ws_size;
  const float* x     = (const float*)d_in[0];
  const float* fp    = (const float*)d_in[1];
  const int*   ei    = (const int*)d_in[2];
  const float* g1_w  = (const float*)d_in[4];
  const float* g1_as = (const float*)d_in[5];
  const float* g1_ad = (const float*)d_in[6];
  const float* g1_b  = (const float*)d_in[7];
  const float* g2_w  = (const float*)d_in[8];
  const float* g2_as = (const float*)d_in[9];
  const float* g2_ad = (const float*)d_in[10];
  const float* g2_b  = (const float*)d_in[11];
  const float* g3_w  = (const float*)d_in[12];
  const float* g3_as = (const float*)d_in[13];
  const float* g3_ad = (const float*)d_in[14];
  const float* g3_b  = (const float*)d_in[15];
  const float* gcn_w = (const float*)d_in[16];
  const float* gcn_b = (const float*)d_in[17];
  const float* t_wq  = (const float*)d_in[18];
  const float* t_wk  = (const float*)d_in[19];
  const float* t_wv  = (const float*)d_in[20];
  const float* t_bq  = (const float*)d_in[21];
  const float* t_bk  = (const float*)d_in[22];
  const float* t_bv  = (const float*)d_in[23];
  const float* t_ws  = (const float*)d_in[24];
  const float* t_bs  = (const float*)d_in[25];
  const float* fc1_w = (const float*)d_in[26];
  const float* fc1_b = (const float*)d_in[27];
  const float* fc2_w = (const float*)d_in[28];
  const float* fc2_b = (const float*)d_in[29];
  const float* b1_w  = (const float*)d_in[30];
  const float* b1_b  = (const float*)d_in[31];
  const float* b2_w  = (const float*)d_in[32];
  const float* b2_b  = (const float*)d_in[33];
  const float* b3_w  = (const float*)d_in[34];
  const float* b3_b  = (const float*)d_in[35];
  const float* b4_w  = (const float*)d_in[36];
  const float* b4_b  = (const float*)d_in[37];

  char* base = (char*)d_ws;
  size_t offb = 0;
  auto alloc = [&](size_t bytes)->void*{
    void* p = base + offb; offb = (offb + bytes + 255) & ~(size_t)255; return p;
  };
  int*   cnt   = (int*)alloc(16384*4);
  int*   off_g = (int*)alloc(4097*4);
  int*   off_t = (int*)alloc(4097*4);
  int*   csr_g = (int*)alloc(12288*4);
  int*   csr_t = (int*)alloc(8192*4);
  float* dis   = (float*)alloc(4096*4);
  float* xpad  = (float*)alloc((size_t)4096*80*4);
  u16*   xph   = (u16*)alloc((size_t)4096*96*2);
  float* alsd  = (float*)alloc((size_t)4096*16*4);
  float* wsv   = (float*)alloc((size_t)2048*8*4);
  float* wdv   = (float*)alloc((size_t)2048*8*4);
  u16*   wsTh  = (u16*)alloc((size_t)16*2048*2);
  u16*   wsTl  = (u16*)alloc((size_t)16*2048*2);
  float* zbuf  = (float*)alloc((size_t)128*512*4);
  float* cbias = (float*)alloc((size_t)6656*4);
  float* w1r   = (float*)alloc((size_t)640*2048*4);
  u16*   gcnT  = (u16*)alloc((size_t)256*512*2);
  u16*   fc1T  = (u16*)alloc((size_t)128*1496*2);
  u16*   fc2T  = (u16*)alloc((size_t)256*128*2);
  u16*   b1T   = (u16*)alloc((size_t)256*1024*2);
  u16*   b2T   = (u16*)alloc((size_t)128*256*2);
  u16*   b3T   = (u16*)alloc((size_t)64*128*2);
  char*  big   = (char*)alloc((size_t)140<<20);

  // ---- overlays (MB offsets in big) ----
  // GAT1
  u16*   y1h   = (u16*)  (big);                         // [0,5)
  u16*   y1l   = (u16*)  (big + ((size_t)5<<20));       // [5,10)
  u16*   w1rth = (u16*)  (big + ((size_t)10<<20));      // [10,13)
  u16*   x1h   = (u16*)  (big + ((size_t)16<<20));      // [16,32)
  u16*   x1l   = (u16*)  (big + ((size_t)32<<20));      // [32,48)
  // GAT2
  u16*   w2th  = (u16*)  (big + ((size_t)48<<20));      // [48,64)  [4096][2048] bf16
  u16*   h2    = (u16*)  (big + ((size_t)64<<20));      // [64,96)  [4096][4096] bf16
  float* acc2  = (float*)(big + ((size_t)96<<20));      // [96,112)
  u16*   x2h   = (u16*)  (big + ((size_t)112<<20));     // [112,120)
  u16*   x2l   = (u16*)  (big + ((size_t)120<<20));     // [120,128)
  // GAT3 (GAT1/x1 regions dead)
  u16*   w3th  = (u16*)  (big);                         // [0,8)   [4096][1024] bf16
  u16*   h3    = (u16*)  (big + ((size_t)8<<20));       // [8,40)  [4096][4096] bf16
  float* acc3  = (float*)(big + ((size_t)40<<20));      // [40,48)
  float* x3    = (float*)(big + ((size_t)48<<20));      // [48,56)
  // TR phase
  u16*   qkvTh = (u16*)  (big);                         // [0,2)   (w3th dead)
  u16*   qkvs  = (u16*)  (big + ((size_t)8<<20));       // [8,64)  bf16 [4096][6656]
  float* xt    = (float*)(big + ((size_t)64<<20));      // [64,72) (h2 dead)

  int* deg_g = cnt;       int* cur_g = cnt+4096;
  int* deg_t = cnt+8192;  int* cur_t = cnt+12288;

  // ---- graph prep ----
  zero_i<<<64,256,0,stream>>>(cnt, 16384);
  hist_k<<<48,256,0,stream>>>(ei, deg_g, deg_t);
  scan4096<<<1,1024,0,stream>>>(deg_g, off_g);
  scan4096<<<1,1024,0,stream>>>(deg_t, off_t);
  scatter_k<<<48,256,0,stream>>>(ei, off_g, cur_g, csr_g, off_t, cur_t, csr_t);
  mkdis<<<16,256,0,stream>>>(deg_g, dis);
  pad_x<<<4096,128,0,stream>>>(x, xpad, xph);
  repack_w1<<<5120,256,0,stream>>>(g1_w, w1r);
  // head weight transposes (bf16)
  tpd<<<dim3(8,16),256,0,stream>>>(gcn_w, 256, 0, 512, 512, gcnT);
  tpd<<<dim3(4,47),256,0,stream>>>(fc1_w, 128, 0, 1489, 1496, fc1T);
  tpd<<<dim3(8,4), 256,0,stream>>>(fc2_w, 256, 0, 128, 128, fc2T);
  tpd<<<dim3(8,32),256,0,stream>>>(b1_w,  256, 0, 1024, 1024, b1T);
  tpd<<<dim3(4,8), 256,0,stream>>>(b2_w,  128, 0, 256, 256, b2T);
  tpd<<<dim3(2,4), 256,0,stream>>>(b3_w,  64,  0, 128, 128, b3T);

  // ---- GAT1 (aggregate-first) ----
  wsvec<<<160,256,0,stream>>>(g1_w, g1_as, g1_ad, wsv, wdv, 78, 8, 2048);
  alk<<<4096,256,0,stream>>>(xpad, wsv, wdv, alsd, 80);
  gat1_gather<<<4096,256,0,stream>>>(xpad, alsd, off_g, csr_g, y1h, y1l);
  tpd<<<dim3(64,20),256,0,stream>>>(w1r, 2048, 0, 640, 640, w1rth);
  mgemm<5,1,float><<<dim3(16,32),256,0,stream>>>(y1h, y1l, 640, w1rth, 640,
                                         nullptr, 2048, 640, g1_b, 0.125f, x1h, x1l);

  // ---- GAT2 ----
  wsvec<<<4096,256,0,stream>>>(g2_w, g2_as, g2_ad, wsv, wdv, 2048, 8, 1024);
  mk_wsT<<<128,256,0,stream>>>(wsv, wdv, wsTh, wsTl, 2048);
  hipMemsetAsync(alsd, 0, (size_t)4096*16*4, stream);
  alk_mm<8><<<dim3(8,32),256,0,stream>>>(x1h, x1l, 2048, wsTh, wsTl, alsd, 2048);
  hipMemsetAsync(acc2, 0, (size_t)4096*1024*4, stream);
  for (int c=0;c<2;c++){
    tpd<<<dim3(128,64),256,0,stream>>>(g2_w, 8192, c*4096, 2048, 2048, w2th);
    mgemm8<<<256,512,0,stream>>>(x1h, 2048, w2th, 2048, h2, 4096, 2048, 16);
    gat_aggN<4,1024><<<4096,256,0,stream>>>(h2, alsd, off_g, csr_g, acc2, c*4);
  }
  finishx2<<<16384,256,0,stream>>>(acc2, g2_b, x2h, x2l, 1023);

  // ---- GAT3 ----
  wsvec<<<2048,256,0,stream>>>(g3_w, g3_as, g3_ad, wsv, wdv, 1024, 8, 512);
  mk_wsT<<<64,256,0,stream>>>(wsv, wdv, wsTh, wsTl, 1024);
  hipMemsetAsync(alsd, 0, (size_t)4096*16*4, stream);
  alk_mm<8><<<dim3(8,32),256,0,stream>>>(x2h, x2l, 1024, wsTh, wsTl, alsd, 1024);
  hipMemsetAsync(acc3, 0, (size_t)4096*512*4, stream);
  tpd<<<dim3(128,32),256,0,stream>>>(g3_w, 4096, 0, 1024, 1024, w3th);
  mgemm8<<<256,512,0,stream>>>(x2h, 1024, w3th, 1024, h3, 4096, 1024, 16);
  gat_aggN<8,512><<<4096,256,0,stream>>>(h3, alsd, off_g, csr_g, acc3, 0);
  finishx<<<8192,256,0,stream>>>(acc3, g3_b, x3, 511);
  pool_gcn<<<128,256,0,stream>>>(x3, dis, off_g, csr_g, zbuf);

  // ---- Transformer branch ----
  tpd<<<dim3(64,3),256,0,stream>>>(t_wq, 2048, 0, 78, 96, qkvTh);
  tpd<<<dim3(64,3),256,0,stream>>>(t_wk, 2048, 0, 78, 96, qkvTh + (size_t)2048*96);
  tpd<<<dim3(64,3),256,0,stream>>>(t_wv, 2048, 0, 78, 96, qkvTh + (size_t)4096*96);
  tpd<<<dim3(16,3),256,0,stream>>>(t_ws, 512,  0, 78, 96, qkvTh + (size_t)6144*96);
  catb<<<26,256,0,stream>>>(t_bq, t_bk, t_bv, t_bs, cbias);
  mgemm<1,0,u16><<<dim3(52,32),256,0,stream>>>(xph, nullptr, 96, qkvTh, 96,
                                         qkvs, 6656, 96, cbias, 0.f, nullptr, nullptr);
  tr_agg<<<4096,256,0,stream>>>(qkvs, off_t, csr_t, xt);

  // ---- fused head ----
  head_k<<<128,256,0,stream>>>(zbuf, xt, fp, gcnT, gcn_b,
                               fc1T, fc1_b, fc2T, fc2_b,
                               b1T, b1_b, b2T, b2_b, b3T, b3_b, b4_w, b4_b,
                               (float*)d_out);
}

// Round 4
// 766.845 us; speedup vs baseline: 1.3256x; 1.3256x over previous
//
#include <hip/hip_runtime.h>

typedef unsigned short u16;
typedef unsigned int   u32;

typedef __bf16 bf16x8 __attribute__((ext_vector_type(8)));
typedef float  f32x4  __attribute__((ext_vector_type(4)));

#define NNODE 4096
#define NEDGE 8192
#define NEG   12288   /* edges incl self-loops */

__device__ __forceinline__ float blo(u32 u){ return __uint_as_float(u<<16); }
__device__ __forceinline__ float bhi(u32 u){ return __uint_as_float(u & 0xffff0000u); }
__device__ __forceinline__ u16 f2b(float f){
  u32 u = __float_as_uint(f);
  u += 0x7fffu + ((u>>16)&1u);
  return (u16)(u>>16);
}
__device__ __forceinline__ void split_bf(float a, u16& hi, u16& lo){
  u32 u = __float_as_uint(a);
  u32 r = u + 0x7fffu + ((u>>16)&1u);
  hi = (u16)(r>>16);
  float h = __uint_as_float(r & 0xffff0000u);
  float l = a - h;
  u32 u2 = __float_as_uint(l);
  lo = (u16)((u2 + 0x7fffu + ((u2>>16)&1u)) >> 16);
}
__device__ __forceinline__ u16 hi_bf(float a){
  u32 u = __float_as_uint(a);
  return (u16)((u + 0x7fffu + ((u>>16)&1u)) >> 16);
}

#define GL2LDS(g,l) __builtin_amdgcn_global_load_lds((const __attribute__((address_space(1))) unsigned int*)(g), (__attribute__((address_space(3))) unsigned int*)(l), 16, 0, 0)

// ---------------- graph prep ----------------
__global__ __launch_bounds__(256) void zero_i(int* p, int n){
  int i = blockIdx.x*256 + threadIdx.x; if (i<n) p[i]=0;
}
__global__ __launch_bounds__(256) void hist_k(const int* __restrict__ ei, int* deg_g, int* deg_t){
  int e = blockIdx.x*256 + threadIdx.x; if (e>=NEG) return;
  int dv = (e<NEDGE) ? ei[NEDGE+e] : e-NEDGE;
  atomicAdd(&deg_g[dv],1);
  if (e<NEDGE) atomicAdd(&deg_t[dv],1);
}
__global__ __launch_bounds__(1024) void scan4096(const int* __restrict__ deg, int* __restrict__ off){
  __shared__ int lds[1024];
  int tid = threadIdx.x;
  int v[4]; int s=0;
  #pragma unroll
  for (int j=0;j<4;j++){ v[j]=deg[tid*4+j]; s+=v[j]; }
  lds[tid]=s; __syncthreads();
  for (int d=1; d<1024; d<<=1){
    int t = (tid>=d) ? lds[tid-d] : 0;
    __syncthreads();
    lds[tid] += t;
    __syncthreads();
  }
  int base = (tid>0) ? lds[tid-1] : 0;
  #pragma unroll
  for (int j=0;j<4;j++){ off[tid*4+j]=base; base+=v[j]; }
  if (tid==1023) off[4096]=base;
}
__global__ __launch_bounds__(256) void scatter_k(const int* __restrict__ ei,
    const int* __restrict__ off_g, int* cur_g, int* csr_g,
    const int* __restrict__ off_t, int* cur_t, int* csr_t){
  int e = blockIdx.x*256 + threadIdx.x; if (e>=NEG) return;
  int s, dv;
  if (e<NEDGE){ s=ei[e]; dv=ei[NEDGE+e]; } else { s=dv=e-NEDGE; }
  int p = atomicAdd(&cur_g[dv],1);
  csr_g[off_g[dv]+p]=s;
  if (e<NEDGE){ int p2 = atomicAdd(&cur_t[dv],1); csr_t[off_t[dv]+p2]=s; }
}
__global__ __launch_bounds__(256) void mkdis(const int* __restrict__ deg, float* dis){
  int i = blockIdx.x*256 + threadIdx.x; if (i>=NNODE) return;
  int d = deg[i]; dis[i] = d>0 ? rsqrtf((float)d) : 0.f;
}
// xpad fp32 [n][80] + xph bf16-hi [n][96]
__global__ __launch_bounds__(128) void pad_x(const float* __restrict__ x, float* __restrict__ xp,
                                             u16* __restrict__ xh){
  int n = blockIdx.x, c = threadIdx.x;
  if (c<96){
    float v = (c<78) ? x[(size_t)n*78+c] : 0.f;
    if (c<80) xp[(size_t)n*80+c] = v;
    xh[(size_t)n*96+c] = hi_bf(v);
  }
}
// W1r[(h*80+k), c] = g1_w[k, h*2048+c], zero-padded k>=78
__global__ __launch_bounds__(256) void repack_w1(const float* __restrict__ g1w, float* __restrict__ w1r){
  int i = blockIdx.x*256 + threadIdx.x;   // 640*2048
  int kk = i >> 11, c = i & 2047;
  int h = kk/80, k2 = kk - h*80;
  w1r[i] = (k2<78) ? g1w[(size_t)k2*16384 + h*2048 + c] : 0.f;
}

// ---------------- transpose + bf16(hi): W[K,Ntot] cols [n0,n0+Nw) -> hi [Nw,Kp] ----------------
__global__ __launch_bounds__(256) void tpd(const float* __restrict__ in, int Ntot, int n0,
    int K, int Kp, u16* __restrict__ outh){
  __shared__ float t[32][33];
  int bx = blockIdx.x*32;   // n in window
  int by = blockIdx.y*32;   // k
  int tx = threadIdx.x & 31, ty = threadIdx.x >> 5;
  for (int i=ty;i<32;i+=8){
    int kk=by+i;
    t[i][tx] = (kk<K) ? in[(size_t)kk*Ntot + n0 + bx + tx] : 0.f;
  }
  __syncthreads();
  for (int i=ty;i<32;i+=8){
    int nn=bx+i, kk=by+tx;
    if (kk<Kp) outh[(size_t)nn*Kp+kk] = hi_bf(t[tx][i]);
  }
}

// ---------------- attention-table pack: [16][Kp] rows 0..7 = ws heads, 8..15 = wd ----------------
__global__ __launch_bounds__(256) void mk_wsT(const float* __restrict__ wsv, const float* __restrict__ wdv,
    u16* __restrict__ th, u16* __restrict__ tl, int Kp){
  int i = blockIdx.x*256 + threadIdx.x;   // over 16*Kp
  if (i >= 16*Kp) return;
  int r = i / Kp, k = i - r*Kp;
  float v = (r<8) ? wsv[k*8+r] : wdv[k*8+(r-8)];
  u16 h,l; split_bf(v,h,l);
  th[i]=h; tl[i]=l;
}

// LDS bank-conflict-free swizzle for [16-row][4x16B] groups staged via global_load_lds:
//   write: lane L fetches logical 16B-col jl = ((L&3) - (L>>3)) & 3  (row = L>>2)
//   read : row rig, logical col q lives at physical slot jp = (q + (rig>>1)) & 3

// ---------------- K-split logits GEMM: alsd[4096][16] += (Ah+Al) * (Bh+Bl)^T ----------------
template<int KS>
__global__ __launch_bounds__(256,4) void alk_mm(
    const u16* __restrict__ Ah, const u16* __restrict__ Al, int lda,
    const u16* __restrict__ Bh, const u16* __restrict__ Bl,
    float* __restrict__ alsd, int K)
{
  __shared__ __align__(16) u16 Ash[128*32], Asl[128*32], Bsh[16*32], Bsl[16*32];
  int tid = threadIdx.x, lane = tid & 63, wave = tid >> 6;
  int bm = blockIdx.y*128;
  int kb = blockIdx.x*(K/KS), ke = kb + K/KS;
  int m16 = lane & 15, quad = lane >> 4;
  int srow = lane >> 2;
  int skk = (((lane & 3) - (srow >> 1)) & 3) * 8;   // swizzled logical col
  int kq  = (((quad + (m16 >> 1)) & 3)) * 8;        // swizzled read slot
  f32x4 acc[2] = {};
  for (int k0=kb; k0<ke; k0+=32){
    __syncthreads();
    #pragma unroll
    for (int t=0;t<2;t++){
      int g = wave + t*4; int row = g*16 + srow;
      GL2LDS(Ah + (size_t)(bm+row)*lda + k0 + skk, &Ash[g*512]);
      GL2LDS(Al + (size_t)(bm+row)*lda + k0 + skk, &Asl[g*512]);
    }
    if (wave==0) GL2LDS(Bh + (size_t)srow*lda + k0 + skk, &Bsh[0]);
    if (wave==1) GL2LDS(Bl + (size_t)srow*lda + k0 + skk, &Bsl[0]);
    __syncthreads();
    bf16x8 bh = *(const bf16x8*)&Bsh[m16*32+kq];
    bf16x8 bl = *(const bf16x8*)&Bsl[m16*32+kq];
    #pragma unroll
    for (int i=0;i<2;i++){
      bf16x8 ah = *(const bf16x8*)&Ash[(wave*32+i*16+m16)*32+kq];
      bf16x8 al = *(const bf16x8*)&Asl[(wave*32+i*16+m16)*32+kq];
      acc[i] = __builtin_amdgcn_mfma_f32_16x16x32_bf16(ah, bh, acc[i],0,0,0);
      acc[i] = __builtin_amdgcn_mfma_f32_16x16x32_bf16(al, bh, acc[i],0,0,0);
      acc[i] = __builtin_amdgcn_mfma_f32_16x16x32_bf16(ah, bl, acc[i],0,0,0);
    }
  }
  #pragma unroll
  for (int i=0;i<2;i++){
    int row0 = bm + wave*32 + i*16 + quad*4;
    #pragma unroll
    for (int r=0;r<4;r++)
      atomicAdd(&alsd[(size_t)(row0+r)*16 + m16], acc[i][r]);
  }
}

// ---------------- MFMA GEMM (m97 staging + swizzle): C = (Ah[+Al]) * Bh^T ----------------
// EPI: 0 plain CT store, 1 +bias CT store, 5 relu(scale*acc+bias) -> split hi/lo only
#define BM 128
#define BN 128
template<int EPI, int SA, typename CT>
__global__ __launch_bounds__(256,4) void mgemm(
    const u16* __restrict__ Ah, const u16* __restrict__ Al, int lda,
    const u16* __restrict__ Bh, int ldb,
    CT* __restrict__ C, int ldc, int K,
    const float* __restrict__ bias, float scale,
    u16* __restrict__ Chi, u16* __restrict__ Clo)
{
  __shared__ __align__(16) u16 Ash[128*32];
  __shared__ __align__(16) u16 Bsh[128*32];
  __shared__ __align__(16) u16 Asl[SA?128*32:16];
  int tid = threadIdx.x;
  int bm = blockIdx.y*BM, bn = blockIdx.x*BN;
  int lane = tid & 63, wave = tid >> 6;
  int wr = (wave>>1)*64, wc = (wave&1)*64;
  int m16 = lane & 15, quad = lane >> 4;
  int srow = lane >> 2;
  int skk = (((lane & 3) - (srow >> 1)) & 3) * 8;   // swizzled fetch col
  int kq  = (((quad + (m16 >> 1)) & 3)) * 8;        // swizzled read slot

  f32x4 acc[4][4] = {};
  for (int k0=0; k0<K; k0+=32){
    __syncthreads();
    #pragma unroll
    for (int t=0;t<2;t++){
      int g = wave + t*4;
      int row = g*16 + srow;
      GL2LDS(Ah + (size_t)(bm+row)*lda + k0 + skk, &Ash[g*512]);
      if (SA) GL2LDS(Al + (size_t)(bm+row)*lda + k0 + skk, &Asl[g*512]);
      GL2LDS(Bh + (size_t)(bn+row)*ldb + k0 + skk, &Bsh[g*512]);
    }
    __syncthreads();
    bf16x8 ah[4], al_[4], bh_[4];
    #pragma unroll
    for (int i=0;i<4;i++){
      ah[i]  = *(const bf16x8*)&Ash[(wr+i*16+m16)*32 + kq];
      if (SA) al_[i] = *(const bf16x8*)&Asl[(wr+i*16+m16)*32 + kq];
    }
    #pragma unroll
    for (int j=0;j<4;j++)
      bh_[j] = *(const bf16x8*)&Bsh[(wc+j*16+m16)*32 + kq];
    #pragma unroll
    for (int i=0;i<4;i++)
      #pragma unroll
      for (int j=0;j<4;j++){
        acc[i][j] = __builtin_amdgcn_mfma_f32_16x16x32_bf16(ah[i], bh_[j], acc[i][j], 0,0,0);
        if (SA) acc[i][j] = __builtin_amdgcn_mfma_f32_16x16x32_bf16(al_[i], bh_[j], acc[i][j], 0,0,0);
      }
  }
  #pragma unroll
  for (int i=0;i<4;i++){
    int row0 = bm + wr + i*16 + quad*4;
    #pragma unroll
    for (int j=0;j<4;j++){
      int col = bn + wc + j*16 + m16;
      float bv = (EPI==1||EPI==5) ? bias[col] : 0.f;
      #pragma unroll
      for (int r=0;r<4;r++){
        float v = acc[i][j][r];
        if constexpr (EPI==5){
          v = fmaxf(v*scale + bv, 0.f);
          size_t idx = (size_t)(row0+r)*ldc + col;
          u16 h_, l_; split_bf(v, h_, l_);
          Chi[idx]=h_; Clo[idx]=l_;
        } else {
          if (EPI==1) v += bv;
          size_t idx = (size_t)(row0+r)*ldc + col;
          if constexpr (sizeof(CT)==2) C[idx] = (CT)f2b(v);
          else C[idx] = (CT)v;
        }
      }
    }
  }
}

// ================= 256x256 / BK=64 / 8-wave 8-phase counted-vmcnt GEMM =================
// C[m][n] = sum_k A[m][k]*B[n][k], all bf16(hi), C bf16.  M,N mult of 256, K mult of 128.
// LDS swizzle: phys_chunk = logical_chunk ^ (row&7) (conflict-free, r2-verified: 0 conflicts).
// r4 change vs r2: the lgkmcnt(0) drain is moved from BEFORE the MFMA cluster to AFTER it
// (just before the closing barrier).  The drain's only correctness role is the WAR hazard
// (this phase's ds_reads must complete before the NEXT phase's stage overwrites the region),
// which only requires completion before the closing barrier.  With the drain post-MFMA the
// compiler emits counted lgkm waits interleaved with the 16 MFMAs, hiding ds_read latency
// under MFMA issue.  RDB8 is issued before RDA8 in read-heavy phases so the first MFMA's
// operands are oldest in the ds queue (first wait ~ lgkmcnt(7)).
// Stage slots (unchanged from r2): ph2:A0,B0(t2) ph3:B1(t2) ph4:A1(t2);
//   ph6:A0,B0(t3) ph7:B1(t3) ph8:A1(t3).  vmcnt(8) at ph4/ph8 forces the OTHER buffer's
//   tile to land before its reads next half-iteration; accumulation order identical to r2.
__device__ __forceinline__ void stA8(const u16* __restrict__ A, int lda, u16* dst,
                                     int bm, int kt, int h, int w, int lane){
  int q = ((lane&7) ^ (lane>>3)) * 8;        // logical chunk for this lane's phys slot
  #pragma unroll
  for (int t=0;t<2;t++){
    int rbase = t*128 + h*64 + w*8;          // wave-uniform, multiple of 8
    int rl = rbase + (lane>>3);
    GL2LDS(A + (size_t)(bm+rl)*lda + kt*64 + q, dst + rbase*64);
  }
}
__device__ __forceinline__ void stB8(const u16* __restrict__ B, int ldb, u16* dst,
                                     int bn, int kt, int nh, int w, int lane){
  int q = ((lane&7) ^ (lane>>3)) * 8;
  #pragma unroll
  for (int t=0;t<2;t++){
    int rbase = (w>>1)*64 + nh*32 + (w&1)*16 + t*8;  // wave-uniform, multiple of 8
    int rl = rbase + (lane>>3);
    GL2LDS(B + (size_t)(bn+rl)*ldb + kt*64 + q, dst + rbase*64);
  }
}
#define LDX8(BUF, ROW, KS) \
  (*(const bf16x8*)&(BUF)[(ROW)*64 + ((((KS)*4 + quad) ^ (m16 & 7)))*8])
#define RDA8(BUF, MH) \
  _Pragma("unroll") for (int mi=0;mi<4;mi++){ \
    a_[mi][0] = LDX8(BUF, wr*128 + ((MH)*4+mi)*16 + m16, 0); \
    a_[mi][1] = LDX8(BUF, wr*128 + ((MH)*4+mi)*16 + m16, 1); }
#define RDB8(BUF, NH, BB) \
  _Pragma("unroll") for (int nj=0;nj<2;nj++){ \
    BB[nj][0] = LDX8(BUF, wc*64 + ((NH)*2+nj)*16 + m16, 0); \
    BB[nj][1] = LDX8(BUF, wc*64 + ((NH)*2+nj)*16 + m16, 1); }
#define MMQ8(MH, NH, BB) \
  _Pragma("unroll") for (int mi=0;mi<4;mi++) \
    _Pragma("unroll") for (int nj=0;nj<2;nj++){ \
      acc[(MH)*4+mi][(NH)*2+nj] = __builtin_amdgcn_mfma_f32_16x16x32_bf16(a_[mi][0], BB[nj][0], acc[(MH)*4+mi][(NH)*2+nj],0,0,0); \
      acc[(MH)*4+mi][(NH)*2+nj] = __builtin_amdgcn_mfma_f32_16x16x32_bf16(a_[mi][1], BB[nj][1], acc[(MH)*4+mi][(NH)*2+nj],0,0,0); }
#define LGKM0 asm volatile("s_waitcnt lgkmcnt(0)" ::: "memory")
#define BAR   __builtin_amdgcn_s_barrier()
#define VM8   asm volatile("s_waitcnt vmcnt(8)" ::: "memory")

__global__ __launch_bounds__(512,2) void mgemm8(
    const u16* __restrict__ A, int lda,
    const u16* __restrict__ B, int ldb,
    u16* __restrict__ C, int ldc, int K, int nbx)
{
  __shared__ __align__(16) u16 As0[16384], As1[16384], Bs0[16384], Bs1[16384];
  int tid = threadIdx.x, lane = tid & 63, w = tid >> 6;
  int m16 = lane & 15, quad = lane >> 4;
  int wr = w >> 2, wc = w & 3;
  // bijective XCD swizzle (gridDim.x % 8 == 0)
  int nwg = (int)gridDim.x, bid = (int)blockIdx.x;
  int wg = (bid & 7)*(nwg>>3) + (bid>>3);
  int by = wg / nbx, bx = wg - by*nbx;
  int bm = by*256, bn = bx*256;
  int NT = K >> 6, NP = NT >> 1;
  f32x4 acc[8][4] = {};
  bf16x8 a_[4][2], b0_[2][2], b1_[2][2];
  // prologue: tile0 (A0,B0,B1,A1) then tile1 (A0,B0,B1,A1) -- 16 loads/wave
  stA8(A,lda,As0,bm,0,0,w,lane);
  stB8(B,ldb,Bs0,bn,0,0,w,lane);
  stB8(B,ldb,Bs0,bn,0,1,w,lane);
  stA8(A,lda,As0,bm,0,1,w,lane);
  stA8(A,lda,As1,bm,1,0,w,lane);
  stB8(B,ldb,Bs1,bn,1,0,w,lane);
  stB8(B,ldb,Bs1,bn,1,1,w,lane);
  stA8(A,lda,As1,bm,1,1,w,lane);
  VM8;                                   // tile0 landed, tile1 in flight
  BAR;
  for (int i=0;i<NP;i++){
    int t2 = 2*i+2; if (t2>NT-1) t2=NT-1;   // clamped garbage-stage on last iter
    int t3 = 2*i+3; if (t3>NT-1) t3=NT-1;
    // ---- ph1: MFMA (0,0) ----
    RDB8(Bs0,0,b0_);
    RDA8(As0,0);
    BAR;
    __builtin_amdgcn_s_setprio(1); MMQ8(0,0,b0_); __builtin_amdgcn_s_setprio(0);
    LGKM0; BAR;
    // ---- ph2: MFMA (0,1) ----
    RDB8(Bs0,1,b1_);
    stA8(A,lda,As0,bm,t2,0,w,lane);
    stB8(B,ldb,Bs0,bn,t2,0,w,lane);
    BAR;
    __builtin_amdgcn_s_setprio(1); MMQ8(0,1,b1_); __builtin_amdgcn_s_setprio(0);
    LGKM0; BAR;
    // ---- ph3: MFMA (1,1) ----
    RDA8(As0,1);
    stB8(B,ldb,Bs0,bn,t2,1,w,lane);
    BAR;
    __builtin_amdgcn_s_setprio(1); MMQ8(1,1,b1_); __builtin_amdgcn_s_setprio(0);
    LGKM0; BAR;
    // ---- ph4: MFMA (1,0) ----
    stA8(A,lda,As0,bm,t2,1,w,lane);
    BAR;
    __builtin_amdgcn_s_setprio(1); MMQ8(1,0,b0_); __builtin_amdgcn_s_setprio(0);
    VM8;                                  // tile 2i+1 fully landed (oldest loads)
    BAR;
    // ---- ph5: MFMA (0,0) tile 2i+1 ----
    RDB8(Bs1,0,b0_);
    RDA8(As1,0);
    BAR;
    __builtin_amdgcn_s_setprio(1); MMQ8(0,0,b0_); __builtin_amdgcn_s_setprio(0);
    LGKM0; BAR;
    // ---- ph6: MFMA (0,1) ----
    RDB8(Bs1,1,b1_);
    stA8(A,lda,As1,bm,t3,0,w,lane);
    stB8(B,ldb,Bs1,bn,t3,0,w,lane);
    BAR;
    __builtin_amdgcn_s_setprio(1); MMQ8(0,1,b1_); __builtin_amdgcn_s_setprio(0);
    LGKM0; BAR;
    // ---- ph7: MFMA (1,1) ----
    RDA8(As1,1);
    stB8(B,ldb,Bs1,bn,t3,1,w,lane);
    BAR;
    __builtin_amdgcn_s_setprio(1); MMQ8(1,1,b1_); __builtin_amdgcn_s_setprio(0);
    LGKM0; BAR;
    // ---- ph8: MFMA (1,0) ----
    stA8(A,lda,As1,bm,t3,1,w,lane);
    BAR;
    __builtin_amdgcn_s_setprio(1); MMQ8(1,0,b0_); __builtin_amdgcn_s_setprio(0);
    VM8;                                  // tile 2i+2 fully landed
    BAR;
  }
  asm volatile("s_waitcnt vmcnt(0)" ::: "memory");    // drain garbage stages
  #pragma unroll
  for (int mi=0;mi<8;mi++){
    int row0 = bm + wr*128 + mi*16 + quad*4;
    #pragma unroll
    for (int nj=0;nj<4;nj++){
      int col = bn + wc*64 + nj*16 + m16;
      #pragma unroll
      for (int r=0;r<4;r++)
        C[(size_t)(row0+r)*ldc + col] = f2b(acc[mi][nj][r]);
    }
  }
}

// ---------------- GAT attention-vector precompute ----------------
__global__ __launch_bounds__(256) void wsvec(const float* __restrict__ W,
    const float* __restrict__ as_, const float* __restrict__ ad_,
    float* __restrict__ ws, float* __restrict__ wd,
    int Kreal, int H, int C)
{
  int wv = blockIdx.x*4 + (threadIdx.x>>6);
  int lane = threadIdx.x & 63;
  int k = wv / H, h = wv - k*H;
  float ps=0.f, pd=0.f;
  if (k < Kreal){
    const float* wr = W + (size_t)k*((size_t)H*C) + (size_t)h*C;
    const float* ar = as_ + (size_t)h*C;
    const float* dr = ad_ + (size_t)h*C;
    for (int c=lane;c<C;c+=64){ float w=wr[c]; ps += w*ar[c]; pd += w*dr[c]; }
  }
  #pragma unroll
  for (int o=32;o;o>>=1){ ps += __shfl_down(ps,o); pd += __shfl_down(pd,o); }
  if (lane==0){ ws[k*H+h]=ps; wd[k*H+h]=pd; }
}
// GAT1 logits (Kp=80), writes alsd[n][16] = [als(8) | ald(8)]
__global__ __launch_bounds__(256) void alk(const float* __restrict__ X,
    const float* __restrict__ ws, const float* __restrict__ wd,
    float* __restrict__ alsd, int Kp)
{
  int n = blockIdx.x, tid = threadIdx.x;
  int hh = tid>>5, l32 = tid&31;
  const float* xr = X + (size_t)n*Kp;
  float ps=0.f, pd=0.f;
  for (int k=l32;k<Kp;k+=32){
    float xv = xr[k];
    ps += xv*ws[k*8+hh];
    pd += xv*wd[k*8+hh];
  }
  #pragma unroll
  for (int o=16;o;o>>=1){ ps += __shfl_down(ps,o,32); pd += __shfl_down(pd,o,32); }
  if (l32==0){ alsd[n*16+hh]=ps; alsd[n*16+8+hh]=pd; }
}

// ---------------- GAT1 aggregate-first gather (emits hi/lo) ----------------
__global__ __launch_bounds__(256) void gat1_gather(
    const float* __restrict__ xpad, const float* __restrict__ alsd,
    const int* __restrict__ off, const int* __restrict__ csr,
    u16* __restrict__ y1h, u16* __restrict__ y1l)
{
  int d = blockIdx.x, tid = threadIdx.x;
  int hh = tid>>5, l32 = tid&31;
  int e0 = off[d], e1 = off[d+1];
  __shared__ float mh[8], lih[8], adh[8];
  __shared__ float wl[32][8];
  __shared__ int sl[32];
  if (tid < 8){
    float ad = alsd[d*16+8+tid]; adh[tid]=ad;
    float m=-1e30f, l=0.f;
    for (int e=e0;e<e1;++e){
      float xv = alsd[csr[e]*16+tid] + ad;
      xv = xv>0.f?xv:0.2f*xv;
      if (xv>m){ l = l*__expf(m-xv)+1.f; m=xv; } else l += __expf(xv-m);
    }
    mh[tid]=m; lih[tid]=1.f/l;
  }
  __syncthreads();
  float acc0=0.f, acc1=0.f, acc2v=0.f;
  for (int cb=e0; cb<e1; cb+=32){
    int ce = min(32, e1-cb);
    if (tid < ce*8){
      int j = tid>>3, h2 = tid&7;
      int s = csr[cb+j];
      if (h2==0) sl[j]=s;
      float xv = alsd[s*16+h2] + adh[h2];
      xv = xv>0.f?xv:0.2f*xv;
      wl[j][h2] = __expf(xv-mh[h2])*lih[h2];
    }
    __syncthreads();
    for (int j=0;j<ce;++j){
      float w = wl[j][hh];
      const float* xr = xpad + (size_t)sl[j]*80;
      acc0 += w*xr[l32];
      acc1 += w*xr[l32+32];
      if (l32 < 16) acc2v += w*xr[l32+64];
    }
    __syncthreads();
  }
  size_t base = (size_t)d*640 + hh*80;
  u16 h_, l_;
  split_bf(acc0, h_, l_); y1h[base+l32]=h_;    y1l[base+l32]=l_;
  split_bf(acc1, h_, l_); y1h[base+l32+32]=h_; y1l[base+l32+32]=l_;
  if (l32<16){ split_bf(acc2v, h_, l_); y1h[base+l32+64]=h_; y1l[base+l32+64]=l_; }
}

// ---------------- all-head chunk aggregation (bf16 h, alsd layout) ----------------
template<int HPC, int C>
__global__ __launch_bounds__(256) void gat_aggN(
    const u16* __restrict__ h, const float* __restrict__ alsd,
    const int* __restrict__ off, const int* __restrict__ csr,
    float* __restrict__ accum, int head0)
{
  constexpr int V = C/256;
  int d = blockIdx.x, tid = threadIdx.x;
  int e0=off[d], e1=off[d+1];
  __shared__ float mh[HPC], lih[HPC], adh[HPC];
  __shared__ float wl[32][HPC];
  __shared__ int sl[32];
  if (tid < HPC){
    float ad = alsd[d*16 + 8 + head0 + tid]; adh[tid]=ad;
    float m=-1e30f,l=0.f;
    for (int e=e0;e<e1;++e){
      float xv = alsd[csr[e]*16 + head0 + tid]+ad;
      xv = xv>0.f?xv:0.2f*xv;
      if (xv>m){ l=l*__expf(m-xv)+1.f; m=xv; } else l+=__expf(xv-m);
    }
    mh[tid]=m; lih[tid]=1.f/l;
  }
  __syncthreads();
  float acc[HPC][V];
  #pragma unroll
  for (int a=0;a<HPC;a++)
    #pragma unroll
    for (int v=0;v<V;v++) acc[a][v]=0.f;
  int c0 = tid*V;
  for (int cb=e0;cb<e1;cb+=32){
    int ce = min(32, e1-cb);
    if (tid < ce*HPC){
      int j = tid/HPC, h2 = tid - j*HPC;
      int s = csr[cb+j];
      if (h2==0) sl[j]=s;
      float xv = alsd[s*16 + head0 + h2] + adh[h2];
      xv = xv>0.f?xv:0.2f*xv;
      wl[j][h2] = __expf(xv-mh[h2])*lih[h2];
    }
    __syncthreads();
    for (int j=0;j<ce;++j){
      const u16* hr = h + (size_t)sl[j]*(HPC*C);
      #pragma unroll
      for (int a=0;a<HPC;a++){
        float w = wl[j][a];
        if constexpr (V==4){
          uint2 u = *(const uint2*)(hr + a*C + c0);
          acc[a][0] += w*blo(u.x); acc[a][1] += w*bhi(u.x);
          acc[a][2] += w*blo(u.y); acc[a][3] += w*bhi(u.y);
        } else {
          u32 u = *(const u32*)(hr + a*C + c0);
          acc[a][0] += w*blo(u); acc[a][1] += w*bhi(u);
        }
      }
    }
    __syncthreads();
  }
  float* ar = accum + (size_t)d*C + c0;
  #pragma unroll
  for (int v=0;v<V;v++){
    float s2 = 0.f;
    #pragma unroll
    for (int a=0;a<HPC;a++) s2 += acc[a][v];
    ar[v] += s2;
  }
}
// x3 = relu(acc/8 + b[c])  (fp32 out, GAT3)
__global__ __launch_bounds__(256) void finishx(const float* __restrict__ accum,
    const float* __restrict__ bias, float* __restrict__ xo, int Cmask){
  int i = blockIdx.x*256 + threadIdx.x;
  int c = i & Cmask;
  xo[i] = fmaxf(accum[i]*0.125f + bias[c], 0.f);
}
// x2 = relu(acc/8 + b[c]) -> hi/lo only (GAT2)
__global__ __launch_bounds__(256) void finishx2(const float* __restrict__ accum,
    const float* __restrict__ bias,
    u16* __restrict__ xh, u16* __restrict__ xl, int Cmask){
  int i = blockIdx.x*256 + threadIdx.x;
  int c = i & Cmask;
  float v = fmaxf(accum[i]*0.125f + bias[c], 0.f);
  u16 h_, l_; split_bf(v, h_, l_);
  xh[i]=h_; xl[i]=l_;
}

// ---------------- pooled GCN aggregation ----------------
__global__ __launch_bounds__(256) void pool_gcn(const float* __restrict__ x3,
    const float* __restrict__ dis, const int* __restrict__ off, const int* __restrict__ csr,
    float* __restrict__ z)
{
  int g = blockIdx.x, tid = threadIdx.x;
  int c0 = tid*2;
  float a0=0.f, a1=0.f;
  for (int dd=0; dd<32; ++dd){
    int d = g*32+dd;
    int e0=off[d], e1=off[d+1];
    float b0=0.f, b1=0.f;
    for (int e=e0;e<e1;++e){
      int s = csr[e]; float ds = dis[s];
      const float* xr = x3 + (size_t)s*512 + c0;
      b0 += ds*xr[0]; b1 += ds*xr[1];
    }
    float dw = dis[d];
    a0 += dw*b0; a1 += dw*b1;
  }
  z[(size_t)g*512+c0]   = a0*(1.f/32.f);
  z[(size_t)g*512+c0+1] = a1*(1.f/32.f);
}

// ---------------- TransformerConv aggregation (bf16 qkvs, logit-cache) ----------------
__global__ __launch_bounds__(256) void tr_agg(
  const u16* __restrict__ qkvs, const int* __restrict__ off, const int* __restrict__ csr,
  float* __restrict__ xt)
{
  int d = blockIdx.x, tid = threadIdx.x;
  int wv = tid>>6, lane = tid&63;
  int e0=off[d], e1=off[d+1];
  __shared__ float osum[4][512];
  __shared__ float sp[4][64];
  float qf[8];
  { uint4 u = *(const uint4*)(qkvs + (size_t)d*6656 + wv*512 + lane*8);
    qf[0]=blo(u.x); qf[1]=bhi(u.x); qf[2]=blo(u.y); qf[3]=bhi(u.y);
    qf[4]=blo(u.z); qf[5]=bhi(u.z); qf[6]=blo(u.w); qf[7]=bhi(u.w); }
  const float scale = 0.04419417382415922f; // 1/sqrt(512)
  float m=-1e30f,l=0.f;
  for (int e=e0;e<e1;++e){
    int s = csr[e];
    uint4 u = *(const uint4*)(qkvs + (size_t)s*6656 + 2048 + wv*512 + lane*8);
    float p = qf[0]*blo(u.x)+qf[1]*bhi(u.x)+qf[2]*blo(u.y)+qf[3]*bhi(u.y)
            + qf[4]*blo(u.z)+qf[5]*bhi(u.z)+qf[6]*blo(u.w)+qf[7]*bhi(u.w);
    #pragma unroll
    for (int o=32;o;o>>=1) p += __shfl_xor(p,o);
    p *= scale;
    int idx = e-e0;
    if (lane==0 && idx<64) sp[wv][idx]=p;
    if (p>m){ l=l*__expf(m-p)+1.f; m=p; } else l+=__expf(p-m);
  }
  float li = (e1>e0)?1.f/l:0.f;
  float acc[8]={0.f,0.f,0.f,0.f,0.f,0.f,0.f,0.f};
  for (int e=e0;e<e1;++e){
    int s = csr[e];
    int idx = e-e0;
    float p;
    if (idx<64) p = sp[wv][idx];
    else {
      uint4 u = *(const uint4*)(qkvs + (size_t)s*6656 + 2048 + wv*512 + lane*8);
      p = qf[0]*blo(u.x)+qf[1]*bhi(u.x)+qf[2]*blo(u.y)+qf[3]*bhi(u.y)
        + qf[4]*blo(u.z)+qf[5]*bhi(u.z)+qf[6]*blo(u.w)+qf[7]*bhi(u.w);
      #pragma unroll
      for (int o=32;o;o>>=1) p += __shfl_xor(p,o);
      p *= scale;
    }
    float w = __expf(p - m)*li;
    uint4 u = *(const uint4*)(qkvs + (size_t)s*6656 + 4096 + wv*512 + lane*8);
    acc[0]+=w*blo(u.x); acc[1]+=w*bhi(u.x); acc[2]+=w*blo(u.y); acc[3]+=w*bhi(u.y);
    acc[4]+=w*blo(u.z); acc[5]+=w*bhi(u.z); acc[6]+=w*blo(u.w); acc[7]+=w*bhi(u.w);
  }
  #pragma unroll
  for (int j=0;j<8;j++) osum[wv][lane*8+j]=acc[j];
  __syncthreads();
  for (int c=tid;c<512;c+=256){
    u16 sk = qkvs[(size_t)d*6656 + 6144 + c];
    float o = (osum[0][c]+osum[1][c]+osum[2][c]+osum[3][c])*0.25f + blo((u32)sk);
    xt[(size_t)d*512+c] = fmaxf(o,0.f);
  }
}

// ---------------- bias concat for qkv GEMM ----------------
__global__ __launch_bounds__(256) void catb(const float* __restrict__ bq, const float* __restrict__ bk,
    const float* __restrict__ bv, const float* __restrict__ bs, float* __restrict__ o){
  int i = blockIdx.x*256 + threadIdx.x; if (i>=6656) return;
  float v;
  if (i<2048) v=bq[i]; else if (i<4096) v=bk[i-2048];
  else if (i<6144) v=bv[i-4096]; else v=bs[i-6144];
  o[i]=v;
}

// ---------------- fused head (bf16 [N,K] weights) ----------------
__device__ __forceinline__ float dotb(const u16* __restrict__ w, const float* __restrict__ s,
                                      int k0, int k1){
  float acc=0.f;
  #pragma unroll 4
  for (int k=k0;k<k1;k+=8){
    uint4 u = *(const uint4*)(w+k);
    float4 s0 = *(const float4*)(s+k);
    float4 s1 = *(const float4*)(s+k+4);
    acc += blo(u.x)*s0.x + bhi(u.x)*s0.y + blo(u.y)*s0.z + bhi(u.y)*s0.w
         + blo(u.z)*s1.x + bhi(u.z)*s1.y + blo(u.w)*s1.z + bhi(u.w)*s1.w;
  }
  return acc;
}
__global__ __launch_bounds__(256) void head_k(
  const float* __restrict__ z, const float* __restrict__ xt, const float* __restrict__ fp,
  const u16* __restrict__ gcnT, const float* __restrict__ gcn_b,
  const u16* __restrict__ fc1T, const float* __restrict__ fc1_b,
  const u16* __restrict__ fc2T, const float* __restrict__ fc2_b,
  const u16* __restrict__ b1T, const float* __restrict__ b1_b,
  const u16* __restrict__ b2T, const float* __restrict__ b2_b,
  const u16* __restrict__ b3T, const float* __restrict__ b3_b,
  const float* __restrict__ b4_w, const float* __restrict__ b4_b,
  float* __restrict__ out)
{
  int g = blockIdx.x, tid = threadIdx.x;
  __shared__ __align__(16) float xc[1024];
  __shared__ __align__(16) float sa[1504];
  __shared__ __align__(16) float sb[256];
  __shared__ __align__(16) float scm[256];
  for (int c=tid;c<512;c+=256) sa[c] = z[(size_t)g*512+c];
  __syncthreads();
  float vgcn = gcn_b[tid] + dotb(gcnT + (size_t)tid*512, sa, 0, 512);
  for (int c=tid;c<512;c+=256){
    float s=0.f;
    for (int i=0;i<32;i++) s += xt[(size_t)(g*32+i)*512 + c];
    xc[256+c] = s*(1.f/32.f);
  }
  xc[tid] = vgcn;
  __syncthreads();
  for (int c=tid;c<1496;c+=256) sa[c] = (c<1489) ? fp[(size_t)g*1489+c] : 0.f;
  __syncthreads();
  { int n = tid & 127, half = tid >> 7;
    sb[tid] = dotb(fc1T + (size_t)n*1496, sa, half?752:0, half?1496:752); }
  __syncthreads();
  if (tid<128) scm[tid] = fmaxf(sb[tid]+sb[tid+128]+fc1_b[tid], 0.f);
  __syncthreads();
  xc[768+tid] = fmaxf(fc2_b[tid] + dotb(fc2T + (size_t)tid*128, scm, 0, 128), 0.f);
  __syncthreads();
  sa[tid] = fmaxf(b1_b[tid] + dotb(b1T + (size_t)tid*1024, xc, 0, 1024), 0.f);
  __syncthreads();
  { int n = tid & 127, half = tid >> 7;
    sb[tid] = dotb(b2T + (size_t)n*256, sa, half*128, half*128+128); }
  __syncthreads();
  if (tid<128) scm[tid] = fmaxf(sb[tid]+sb[tid+128]+b2_b[tid], 0.f);
  __syncthreads();
  { int n = tid & 63, part = tid >> 6;
    sb[tid] = dotb(b3T + (size_t)n*128, scm, part*32, part*32+32); }
  __syncthreads();
  if (tid<64) sa[tid] = fmaxf(sb[tid]+sb[tid+64]+sb[tid+128]+sb[tid+192]+b3_b[tid], 0.f);
  __syncthreads();
  if (tid<64){
    float p = sa[tid]*b4_w[tid];
    #pragma unroll
    for (int o=32;o;o>>=1) p += __shfl_down(p,o);
    if (tid==0) out[g] = 1.f/(1.f+__expf(-(p + b4_b[0])));
  }
}

extern "C" void kernel_launch(void* const* d_in, const int* in_sizes, int n_in,
                              void* d_out, int out_size, void* d_ws, size_t ws_size,
                              hipStream_t stream)
{
  (void)in_sizes; (void)n_in; (void)out_size; (void)ws_size;
  const float* x     = (const float*)d_in[0];
  const float* fp    = (const float*)d_in[1];
  const int*   ei    = (const int*)d_in[2];
  const float* g1_w  = (const float*)d_in[4];
  const float* g1_as = (const float*)d_in[5];
  const float* g1_ad = (const float*)d_in[6];
  const float* g1_b  = (const float*)d_in[7];
  const float* g2_w  = (const float*)d_in[8];
  const float* g2_as = (const float*)d_in[9];
  const float* g2_ad = (const float*)d_in[10];
  const float* g2_b  = (const float*)d_in[11];
  const float* g3_w  = (const float*)d_in[12];
  const float* g3_as = (const float*)d_in[13];
  const float* g3_ad = (const float*)d_in[14];
  const float* g3_b  = (const float*)d_in[15];
  const float* gcn_w = (const float*)d_in[16];
  const float* gcn_b = (const float*)d_in[17];
  const float* t_wq  = (const float*)d_in[18];
  const float* t_wk  = (const float*)d_in[19];
  const float* t_wv  = (const float*)d_in[20];
  const float* t_bq  = (const float*)d_in[21];
  const float* t_bk  = (const float*)d_in[22];
  const float* t_bv  = (const float*)d_in[23];
  const float* t_ws  = (const float*)d_in[24];
  const float* t_bs  = (const float*)d_in[25];
  const float* fc1_w = (const float*)d_in[26];
  const float* fc1_b = (const float*)d_in[27];
  const float* fc2_w = (const float*)d_in[28];
  const float* fc2_b = (const float*)d_in[29];
  const float* b1_w  = (const float*)d_in[30];
  const float* b1_b  = (const float*)d_in[31];
  const float* b2_w  = (const float*)d_in[32];
  const float* b2_b  = (const float*)d_in[33];
  const float* b3_w  = (const float*)d_in[34];
  const float* b3_b  = (const float*)d_in[35];
  const float* b4_w  = (const float*)d_in[36];
  const float* b4_b  = (const float*)d_in[37];

  char* base = (char*)d_ws;
  size_t offb = 0;
  auto alloc = [&](size_t bytes)->void*{
    void* p = base + offb; offb = (offb + bytes + 255) & ~(size_t)255; return p;
  };
  int*   cnt   = (int*)alloc(16384*4);
  int*   off_g = (int*)alloc(4097*4);
  int*   off_t = (int*)alloc(4097*4);
  int*   csr_g = (int*)alloc(12288*4);
  int*   csr_t = (int*)alloc(8192*4);
  float* dis   = (float*)alloc(4096*4);
  float* xpad  = (float*)alloc((size_t)4096*80*4);
  u16*   xph   = (u16*)alloc((size_t)4096*96*2);
  float* alsd  = (float*)alloc((size_t)4096*16*4);
  float* wsv   = (float*)alloc((size_t)2048*8*4);
  float* wdv   = (float*)alloc((size_t)2048*8*4);
  u16*   wsTh  = (u16*)alloc((size_t)16*2048*2);
  u16*   wsTl  = (u16*)alloc((size_t)16*2048*2);
  float* zbuf  = (float*)alloc((size_t)128*512*4);
  float* cbias = (float*)alloc((size_t)6656*4);
  float* w1r   = (float*)alloc((size_t)640*2048*4);
  u16*   gcnT  = (u16*)alloc((size_t)256*512*2);
  u16*   fc1T  = (u16*)alloc((size_t)128*1496*2);
  u16*   fc2T  = (u16*)alloc((size_t)256*128*2);
  u16*   b1T   = (u16*)alloc((size_t)256*1024*2);
  u16*   b2T   = (u16*)alloc((size_t)128*256*2);
  u16*   b3T   = (u16*)alloc((size_t)64*128*2);
  char*  big   = (char*)alloc((size_t)140<<20);

  // ---- overlays (MB offsets in big) ----
  // GAT1
  u16*   y1h   = (u16*)  (big);                         // [0,5)
  u16*   y1l   = (u16*)  (big + ((size_t)5<<20));       // [5,10)
  u16*   w1rth = (u16*)  (big + ((size_t)10<<20));      // [10,13)
  u16*   x1h   = (u16*)  (big + ((size_t)16<<20));      // [16,32)
  u16*   x1l   = (u16*)  (big + ((size_t)32<<20));      // [32,48)
  // GAT2
  u16*   w2th  = (u16*)  (big + ((size_t)48<<20));      // [48,64)  [4096][2048] bf16
  u16*   h2    = (u16*)  (big + ((size_t)64<<20));      // [64,96)  [4096][4096] bf16
  float* acc2  = (float*)(big + ((size_t)96<<20));      // [96,112)
  u16*   x2h   = (u16*)  (big + ((size_t)112<<20));     // [112,120)
  u16*   x2l   = (u16*)  (big + ((size_t)120<<20));     // [120,128)
  // GAT3 (GAT1/x1 regions dead)
  u16*   w3th  = (u16*)  (big);                         // [0,8)   [4096][1024] bf16
  u16*   h3    = (u16*)  (big + ((size_t)8<<20));       // [8,40)  [4096][4096] bf16
  float* acc3  = (float*)(big + ((size_t)40<<20));      // [40,48)
  float* x3    = (float*)(big + ((size_t)48<<20));      // [48,56)
  // TR phase
  u16*   qkvTh = (u16*)  (big);                         // [0,2)   (w3th dead)
  u16*   qkvs  = (u16*)  (big + ((size_t)8<<20));       // [8,64)  bf16 [4096][6656]
  float* xt    = (float*)(big + ((size_t)64<<20));      // [64,72) (h2 dead)

  int* deg_g = cnt;       int* cur_g = cnt+4096;
  int* deg_t = cnt+8192;  int* cur_t = cnt+12288;

  // ---- graph prep ----
  zero_i<<<64,256,0,stream>>>(cnt, 16384);
  hist_k<<<48,256,0,stream>>>(ei, deg_g, deg_t);
  scan4096<<<1,1024,0,stream>>>(deg_g, off_g);
  scan4096<<<1,1024,0,stream>>>(deg_t, off_t);
  scatter_k<<<48,256,0,stream>>>(ei, off_g, cur_g, csr_g, off_t, cur_t, csr_t);
  mkdis<<<16,256,0,stream>>>(deg_g, dis);
  pad_x<<<4096,128,0,stream>>>(x, xpad, xph);
  repack_w1<<<5120,256,0,stream>>>(g1_w, w1r);
  // head weight transposes (bf16)
  tpd<<<dim3(8,16),256,0,stream>>>(gcn_w, 256, 0, 512, 512, gcnT);
  tpd<<<dim3(4,47),256,0,stream>>>(fc1_w, 128, 0, 1489, 1496, fc1T);
  tpd<<<dim3(8,4), 256,0,stream>>>(fc2_w, 256, 0, 128, 128, fc2T);
  tpd<<<dim3(8,32),256,0,stream>>>(b1_w,  256, 0, 1024, 1024, b1T);
  tpd<<<dim3(4,8), 256,0,stream>>>(b2_w,  128, 0, 256, 256, b2T);
  tpd<<<dim3(2,4), 256,0,stream>>>(b3_w,  64,  0, 128, 128, b3T);

  // ---- GAT1 (aggregate-first) ----
  wsvec<<<160,256,0,stream>>>(g1_w, g1_as, g1_ad, wsv, wdv, 78, 8, 2048);
  alk<<<4096,256,0,stream>>>(xpad, wsv, wdv, alsd, 80);
  gat1_gather<<<4096,256,0,stream>>>(xpad, alsd, off_g, csr_g, y1h, y1l);
  tpd<<<dim3(64,20),256,0,stream>>>(w1r, 2048, 0, 640, 640, w1rth);
  mgemm<5,1,float><<<dim3(16,32),256,0,stream>>>(y1h, y1l, 640, w1rth, 640,
                                         nullptr, 2048, 640, g1_b, 0.125f, x1h, x1l);

  // ---- GAT2 ----
  wsvec<<<4096,256,0,stream>>>(g2_w, g2_as, g2_ad, wsv, wdv, 2048, 8, 1024);
  mk_wsT<<<128,256,0,stream>>>(wsv, wdv, wsTh, wsTl, 2048);
  hipMemsetAsync(alsd, 0, (size_t)4096*16*4, stream);
  alk_mm<8><<<dim3(8,32),256,0,stream>>>(x1h, x1l, 2048, wsTh, wsTl, alsd, 2048);
  hipMemsetAsync(acc2, 0, (size_t)4096*1024*4, stream);
  for (int c=0;c<2;c++){
    tpd<<<dim3(128,64),256,0,stream>>>(g2_w, 8192, c*4096, 2048, 2048, w2th);
    mgemm8<<<256,512,0,stream>>>(x1h, 2048, w2th, 2048, h2, 4096, 2048, 16);
    gat_aggN<4,1024><<<4096,256,0,stream>>>(h2, alsd, off_g, csr_g, acc2, c*4);
  }
  finishx2<<<16384,256,0,stream>>>(acc2, g2_b, x2h, x2l, 1023);

  // ---- GAT3 ----
  wsvec<<<2048,256,0,stream>>>(g3_w, g3_as, g3_ad, wsv, wdv, 1024, 8, 512);
  mk_wsT<<<64,256,0,stream>>>(wsv, wdv, wsTh, wsTl, 1024);
  hipMemsetAsync(alsd, 0, (size_t)4096*16*4, stream);
  alk_mm<8><<<dim3(8,32),256,0,stream>>>(x2h, x2l, 1024, wsTh, wsTl, alsd, 1024);
  hipMemsetAsync(acc3, 0, (size_t)4096*512*4, stream);
  tpd<<<dim3(128,32),256,0,stream>>>(g3_w, 4096, 0, 1024, 1024, w3th);
  mgemm8<<<256,512,0,stream>>>(x2h, 1024, w3th, 1024, h3, 4096, 1024, 16);
  gat_aggN<8,512><<<4096,256,0,stream>>>(h3, alsd, off_g, csr_g, acc3, 0);
  finishx<<<8192,256,0,stream>>>(acc3, g3_b, x3, 511);
  pool_gcn<<<128,256,0,stream>>>(x3, dis, off_g, csr_g, zbuf);

  // ---- Transformer branch ----
  tpd<<<dim3(64,3),256,0,stream>>>(t_wq, 2048, 0, 78, 96, qkvTh);
  tpd<<<dim3(64,3),256,0,stream>>>(t_wk, 2048, 0, 78, 96, qkvTh + (size_t)2048*96);
  tpd<<<dim3(64,3),256,0,stream>>>(t_wv, 2048, 0, 78, 96, qkvTh + (size_t)4096*96);
  tpd<<<dim3(16,3),256,0,stream>>>(t_ws, 512,  0, 78, 96, qkvTh + (size_t)6144*96);
  catb<<<26,256,0,stream>>>(t_bq, t_bk, t_bv, t_bs, cbias);
  mgemm<1,0,u16><<<dim3(52,32),256,0,stream>>>(xph, nullptr, 96, qkvTh, 96,
                                         qkvs, 6656, 96, cbias, 0.f, nullptr, nullptr);
  tr_agg<<<4096,256,0,stream>>>(qkvs, off_t, csr_t, xt);

  // ---- fused head ----
  head_k<<<128,256,0,stream>>>(zbuf, xt, fp, gcnT, gcn_b,
                               fc1T, fc1_b, fc2T, fc2_b,
                               b1T, b1_b, b2T, b2_b, b3T, b3_b, b4_w, b4_b,
                               (float*)d_out);
}

// Round 5
// 753.459 us; speedup vs baseline: 1.3492x; 1.0178x over previous
//
#include <hip/hip_runtime.h>

typedef unsigned short u16;
typedef unsigned int   u32;

typedef __bf16 bf16x8 __attribute__((ext_vector_type(8)));
typedef float  f32x4  __attribute__((ext_vector_type(4)));

#define NNODE 4096
#define NEDGE 8192
#define NEG   12288   /* edges incl self-loops */

__device__ __forceinline__ float blo(u32 u){ return __uint_as_float(u<<16); }
__device__ __forceinline__ float bhi(u32 u){ return __uint_as_float(u & 0xffff0000u); }
__device__ __forceinline__ u16 f2b(float f){
  u32 u = __float_as_uint(f);
  u += 0x7fffu + ((u>>16)&1u);
  return (u16)(u>>16);
}
__device__ __forceinline__ void split_bf(float a, u16& hi, u16& lo){
  u32 u = __float_as_uint(a);
  u32 r = u + 0x7fffu + ((u>>16)&1u);
  hi = (u16)(r>>16);
  float h = __uint_as_float(r & 0xffff0000u);
  float l = a - h;
  u32 u2 = __float_as_uint(l);
  lo = (u16)((u2 + 0x7fffu + ((u2>>16)&1u)) >> 16);
}
__device__ __forceinline__ u16 hi_bf(float a){
  u32 u = __float_as_uint(a);
  return (u16)((u + 0x7fffu + ((u>>16)&1u)) >> 16);
}

#define GL2LDS(g,l) __builtin_amdgcn_global_load_lds((const __attribute__((address_space(1))) unsigned int*)(g), (__attribute__((address_space(3))) unsigned int*)(l), 16, 0, 0)

// ---------------- graph prep ----------------
__global__ __launch_bounds__(256) void zero_i(int* p, int n){
  int i = blockIdx.x*256 + threadIdx.x; if (i<n) p[i]=0;
}
__global__ __launch_bounds__(256) void hist_k(const int* __restrict__ ei, int* deg_g, int* deg_t){
  int e = blockIdx.x*256 + threadIdx.x; if (e>=NEG) return;
  int dv = (e<NEDGE) ? ei[NEDGE+e] : e-NEDGE;
  atomicAdd(&deg_g[dv],1);
  if (e<NEDGE) atomicAdd(&deg_t[dv],1);
}
__global__ __launch_bounds__(1024) void scan4096(const int* __restrict__ deg, int* __restrict__ off){
  __shared__ int lds[1024];
  int tid = threadIdx.x;
  int v[4]; int s=0;
  #pragma unroll
  for (int j=0;j<4;j++){ v[j]=deg[tid*4+j]; s+=v[j]; }
  lds[tid]=s; __syncthreads();
  for (int d=1; d<1024; d<<=1){
    int t = (tid>=d) ? lds[tid-d] : 0;
    __syncthreads();
    lds[tid] += t;
    __syncthreads();
  }
  int base = (tid>0) ? lds[tid-1] : 0;
  #pragma unroll
  for (int j=0;j<4;j++){ off[tid*4+j]=base; base+=v[j]; }
  if (tid==1023) off[4096]=base;
}
__global__ __launch_bounds__(256) void scatter_k(const int* __restrict__ ei,
    const int* __restrict__ off_g, int* cur_g, int* csr_g,
    const int* __restrict__ off_t, int* cur_t, int* csr_t){
  int e = blockIdx.x*256 + threadIdx.x; if (e>=NEG) return;
  int s, dv;
  if (e<NEDGE){ s=ei[e]; dv=ei[NEDGE+e]; } else { s=dv=e-NEDGE; }
  int p = atomicAdd(&cur_g[dv],1);
  csr_g[off_g[dv]+p]=s;
  if (e<NEDGE){ int p2 = atomicAdd(&cur_t[dv],1); csr_t[off_t[dv]+p2]=s; }
}
__global__ __launch_bounds__(256) void mkdis(const int* __restrict__ deg, float* dis){
  int i = blockIdx.x*256 + threadIdx.x; if (i>=NNODE) return;
  int d = deg[i]; dis[i] = d>0 ? rsqrtf((float)d) : 0.f;
}
// xpad fp32 [n][80] + xph bf16-hi [n][96]
__global__ __launch_bounds__(128) void pad_x(const float* __restrict__ x, float* __restrict__ xp,
                                             u16* __restrict__ xh){
  int n = blockIdx.x, c = threadIdx.x;
  if (c<96){
    float v = (c<78) ? x[(size_t)n*78+c] : 0.f;
    if (c<80) xp[(size_t)n*80+c] = v;
    xh[(size_t)n*96+c] = hi_bf(v);
  }
}
// W1r[(h*80+k), c] = g1_w[k, h*2048+c], zero-padded k>=78
__global__ __launch_bounds__(256) void repack_w1(const float* __restrict__ g1w, float* __restrict__ w1r){
  int i = blockIdx.x*256 + threadIdx.x;   // 640*2048
  int kk = i >> 11, c = i & 2047;
  int h = kk/80, k2 = kk - h*80;
  w1r[i] = (k2<78) ? g1w[(size_t)k2*16384 + h*2048 + c] : 0.f;
}

// ---------------- transpose + bf16(hi): W[K,Ntot] cols [n0,n0+Nw) -> hi [Nw,Kp] ----------------
__global__ __launch_bounds__(256) void tpd(const float* __restrict__ in, int Ntot, int n0,
    int K, int Kp, u16* __restrict__ outh){
  __shared__ float t[32][33];
  int bx = blockIdx.x*32;   // n in window
  int by = blockIdx.y*32;   // k
  int tx = threadIdx.x & 31, ty = threadIdx.x >> 5;
  for (int i=ty;i<32;i+=8){
    int kk=by+i;
    t[i][tx] = (kk<K) ? in[(size_t)kk*Ntot + n0 + bx + tx] : 0.f;
  }
  __syncthreads();
  for (int i=ty;i<32;i+=8){
    int nn=bx+i, kk=by+tx;
    if (kk<Kp) outh[(size_t)nn*Kp+kk] = hi_bf(t[tx][i]);
  }
}

// ---------------- attention-table pack: [16][Kp] rows 0..7 = ws heads, 8..15 = wd ----------------
__global__ __launch_bounds__(256) void mk_wsT(const float* __restrict__ wsv, const float* __restrict__ wdv,
    u16* __restrict__ th, u16* __restrict__ tl, int Kp){
  int i = blockIdx.x*256 + threadIdx.x;   // over 16*Kp
  if (i >= 16*Kp) return;
  int r = i / Kp, k = i - r*Kp;
  float v = (r<8) ? wsv[k*8+r] : wdv[k*8+(r-8)];
  u16 h,l; split_bf(v,h,l);
  th[i]=h; tl[i]=l;
}

// LDS bank-conflict-free swizzle for [16-row][4x16B] groups staged via global_load_lds:
//   write: lane L fetches logical 16B-col jl = ((L&3) - (L>>3)) & 3  (row = L>>2)
//   read : row rig, logical col q lives at physical slot jp = (q + (rig>>1)) & 3

// ---------------- K-split logits GEMM: alsd[4096][16] += (Ah+Al) * (Bh+Bl)^T ----------------
template<int KS>
__global__ __launch_bounds__(256,4) void alk_mm(
    const u16* __restrict__ Ah, const u16* __restrict__ Al, int lda,
    const u16* __restrict__ Bh, const u16* __restrict__ Bl,
    float* __restrict__ alsd, int K)
{
  __shared__ __align__(16) u16 Ash[128*32], Asl[128*32], Bsh[16*32], Bsl[16*32];
  int tid = threadIdx.x, lane = tid & 63, wave = tid >> 6;
  int bm = blockIdx.y*128;
  int kb = blockIdx.x*(K/KS), ke = kb + K/KS;
  int m16 = lane & 15, quad = lane >> 4;
  int srow = lane >> 2;
  int skk = (((lane & 3) - (srow >> 1)) & 3) * 8;   // swizzled logical col
  int kq  = (((quad + (m16 >> 1)) & 3)) * 8;        // swizzled read slot
  f32x4 acc[2] = {};
  for (int k0=kb; k0<ke; k0+=32){
    __syncthreads();
    #pragma unroll
    for (int t=0;t<2;t++){
      int g = wave + t*4; int row = g*16 + srow;
      GL2LDS(Ah + (size_t)(bm+row)*lda + k0 + skk, &Ash[g*512]);
      GL2LDS(Al + (size_t)(bm+row)*lda + k0 + skk, &Asl[g*512]);
    }
    if (wave==0) GL2LDS(Bh + (size_t)srow*lda + k0 + skk, &Bsh[0]);
    if (wave==1) GL2LDS(Bl + (size_t)srow*lda + k0 + skk, &Bsl[0]);
    __syncthreads();
    bf16x8 bh = *(const bf16x8*)&Bsh[m16*32+kq];
    bf16x8 bl = *(const bf16x8*)&Bsl[m16*32+kq];
    #pragma unroll
    for (int i=0;i<2;i++){
      bf16x8 ah = *(const bf16x8*)&Ash[(wave*32+i*16+m16)*32+kq];
      bf16x8 al = *(const bf16x8*)&Asl[(wave*32+i*16+m16)*32+kq];
      acc[i] = __builtin_amdgcn_mfma_f32_16x16x32_bf16(ah, bh, acc[i],0,0,0);
      acc[i] = __builtin_amdgcn_mfma_f32_16x16x32_bf16(al, bh, acc[i],0,0,0);
      acc[i] = __builtin_amdgcn_mfma_f32_16x16x32_bf16(ah, bl, acc[i],0,0,0);
    }
  }
  #pragma unroll
  for (int i=0;i<2;i++){
    int row0 = bm + wave*32 + i*16 + quad*4;
    #pragma unroll
    for (int r=0;r<4;r++)
      atomicAdd(&alsd[(size_t)(row0+r)*16 + m16], acc[i][r]);
  }
}

// ---------------- MFMA GEMM (m97 staging + swizzle): C = (Ah[+Al]) * Bh^T ----------------
// EPI: 0 plain CT store, 1 +bias CT store, 5 relu(scale*acc+bias) -> split hi/lo only
#define BM 128
#define BN 128
template<int EPI, int SA, typename CT>
__global__ __launch_bounds__(256,4) void mgemm(
    const u16* __restrict__ Ah, const u16* __restrict__ Al, int lda,
    const u16* __restrict__ Bh, int ldb,
    CT* __restrict__ C, int ldc, int K,
    const float* __restrict__ bias, float scale,
    u16* __restrict__ Chi, u16* __restrict__ Clo)
{
  __shared__ __align__(16) u16 Ash[128*32];
  __shared__ __align__(16) u16 Bsh[128*32];
  __shared__ __align__(16) u16 Asl[SA?128*32:16];
  int tid = threadIdx.x;
  int bm = blockIdx.y*BM, bn = blockIdx.x*BN;
  int lane = tid & 63, wave = tid >> 6;
  int wr = (wave>>1)*64, wc = (wave&1)*64;
  int m16 = lane & 15, quad = lane >> 4;
  int srow = lane >> 2;
  int skk = (((lane & 3) - (srow >> 1)) & 3) * 8;   // swizzled fetch col
  int kq  = (((quad + (m16 >> 1)) & 3)) * 8;        // swizzled read slot

  f32x4 acc[4][4] = {};
  for (int k0=0; k0<K; k0+=32){
    __syncthreads();
    #pragma unroll
    for (int t=0;t<2;t++){
      int g = wave + t*4;
      int row = g*16 + srow;
      GL2LDS(Ah + (size_t)(bm+row)*lda + k0 + skk, &Ash[g*512]);
      if (SA) GL2LDS(Al + (size_t)(bm+row)*lda + k0 + skk, &Asl[g*512]);
      GL2LDS(Bh + (size_t)(bn+row)*ldb + k0 + skk, &Bsh[g*512]);
    }
    __syncthreads();
    bf16x8 ah[4], al_[4], bh_[4];
    #pragma unroll
    for (int i=0;i<4;i++){
      ah[i]  = *(const bf16x8*)&Ash[(wr+i*16+m16)*32 + kq];
      if (SA) al_[i] = *(const bf16x8*)&Asl[(wr+i*16+m16)*32 + kq];
    }
    #pragma unroll
    for (int j=0;j<4;j++)
      bh_[j] = *(const bf16x8*)&Bsh[(wc+j*16+m16)*32 + kq];
    #pragma unroll
    for (int i=0;i<4;i++)
      #pragma unroll
      for (int j=0;j<4;j++){
        acc[i][j] = __builtin_amdgcn_mfma_f32_16x16x32_bf16(ah[i], bh_[j], acc[i][j], 0,0,0);
        if (SA) acc[i][j] = __builtin_amdgcn_mfma_f32_16x16x32_bf16(al_[i], bh_[j], acc[i][j], 0,0,0);
      }
  }
  #pragma unroll
  for (int i=0;i<4;i++){
    int row0 = bm + wr + i*16 + quad*4;
    #pragma unroll
    for (int j=0;j<4;j++){
      int col = bn + wc + j*16 + m16;
      float bv = (EPI==1||EPI==5) ? bias[col] : 0.f;
      #pragma unroll
      for (int r=0;r<4;r++){
        float v = acc[i][j][r];
        if constexpr (EPI==5){
          v = fmaxf(v*scale + bv, 0.f);
          size_t idx = (size_t)(row0+r)*ldc + col;
          u16 h_, l_; split_bf(v, h_, l_);
          Chi[idx]=h_; Clo[idx]=l_;
        } else {
          if (EPI==1) v += bv;
          size_t idx = (size_t)(row0+r)*ldc + col;
          if constexpr (sizeof(CT)==2) C[idx] = (CT)f2b(v);
          else C[idx] = (CT)v;
        }
      }
    }
  }
}

// ================= 256x256 / BK=64 / 8-wave 8-phase SINGLE-BARRIER GEMM =================
// C[m][n] = sum_k A[m][k]*B[n][k], all bf16(hi), C bf16.  M,N mult of 256, K mult of 128.
// LDS swizzle: phys_chunk = logical_chunk ^ (row&7) (conflict-free, r2-verified: 0 conflicts).
// r5 change vs r2/r4: ONE barrier per phase.  Phase = {reads(p) | stage; lgkmcnt(0);
// [vmcnt(8) at ph4/ph8]; BAR; setprio(1) MFMA(p) setprio(0)}.  MFMA(p) and reads(p+1)
// now share an inter-barrier window, so waves skew: one wave's MFMA overlaps other
// waves' ds_reads (LDS pipe ~2300cyc/K-tile and MFMA pipe ~2500cyc/K-tile can overlap
// instead of serializing in disjoint barrier windows).  Correctness:
//  - WAR: each wave drains its own reads (lgkmcnt(0)) BEFORE the barrier; the stage
//    overwriting that region is issued only AFTER that barrier -> no read-under-write.
//    Window-local read/stage pairs touch disjoint regions (ph2: stage A0,B0(t2) read
//    B1(cur); ph3: stage B1(t2) read A1(cur); ph4: stage A1(t2), no reads).
//  - RAW: vmcnt(8) before the ph4/ph8 barrier forces the tile needed next half-iteration
//    to land (same queue accounting as r2); the barrier publishes it cross-wave.
//  - MFMA operands are in registers by barrier time.
// Accumulation order identical to r2 -> bitwise-identical C.
__device__ __forceinline__ void stA8(const u16* __restrict__ A, int lda, u16* dst,
                                     int bm, int kt, int h, int w, int lane){
  int q = ((lane&7) ^ (lane>>3)) * 8;        // logical chunk for this lane's phys slot
  #pragma unroll
  for (int t=0;t<2;t++){
    int rbase = t*128 + h*64 + w*8;          // wave-uniform, multiple of 8
    int rl = rbase + (lane>>3);
    GL2LDS(A + (size_t)(bm+rl)*lda + kt*64 + q, dst + rbase*64);
  }
}
__device__ __forceinline__ void stB8(const u16* __restrict__ B, int ldb, u16* dst,
                                     int bn, int kt, int nh, int w, int lane){
  int q = ((lane&7) ^ (lane>>3)) * 8;
  #pragma unroll
  for (int t=0;t<2;t++){
    int rbase = (w>>1)*64 + nh*32 + (w&1)*16 + t*8;  // wave-uniform, multiple of 8
    int rl = rbase + (lane>>3);
    GL2LDS(B + (size_t)(bn+rl)*ldb + kt*64 + q, dst + rbase*64);
  }
}
#define LDX8(BUF, ROW, KS) \
  (*(const bf16x8*)&(BUF)[(ROW)*64 + ((((KS)*4 + quad) ^ (m16 & 7)))*8])
#define RDA8(BUF, MH) \
  _Pragma("unroll") for (int mi=0;mi<4;mi++){ \
    a_[mi][0] = LDX8(BUF, wr*128 + ((MH)*4+mi)*16 + m16, 0); \
    a_[mi][1] = LDX8(BUF, wr*128 + ((MH)*4+mi)*16 + m16, 1); }
#define RDB8(BUF, NH, BB) \
  _Pragma("unroll") for (int nj=0;nj<2;nj++){ \
    BB[nj][0] = LDX8(BUF, wc*64 + ((NH)*2+nj)*16 + m16, 0); \
    BB[nj][1] = LDX8(BUF, wc*64 + ((NH)*2+nj)*16 + m16, 1); }
#define MMQ8(MH, NH, BB) \
  _Pragma("unroll") for (int mi=0;mi<4;mi++) \
    _Pragma("unroll") for (int nj=0;nj<2;nj++){ \
      acc[(MH)*4+mi][(NH)*2+nj] = __builtin_amdgcn_mfma_f32_16x16x32_bf16(a_[mi][0], BB[nj][0], acc[(MH)*4+mi][(NH)*2+nj],0,0,0); \
      acc[(MH)*4+mi][(NH)*2+nj] = __builtin_amdgcn_mfma_f32_16x16x32_bf16(a_[mi][1], BB[nj][1], acc[(MH)*4+mi][(NH)*2+nj],0,0,0); }
#define LGKM0 asm volatile("s_waitcnt lgkmcnt(0)" ::: "memory")
#define BAR   __builtin_amdgcn_s_barrier()
#define VM8   asm volatile("s_waitcnt vmcnt(8)" ::: "memory")
#define MMRUN(MH,NH,BB) \
  __builtin_amdgcn_s_setprio(1); MMQ8(MH,NH,BB); __builtin_amdgcn_s_setprio(0);

__global__ __launch_bounds__(512,2) void mgemm8(
    const u16* __restrict__ A, int lda,
    const u16* __restrict__ B, int ldb,
    u16* __restrict__ C, int ldc, int K, int nbx)
{
  __shared__ __align__(16) u16 As0[16384], As1[16384], Bs0[16384], Bs1[16384];
  int tid = threadIdx.x, lane = tid & 63, w = tid >> 6;
  int m16 = lane & 15, quad = lane >> 4;
  int wr = w >> 2, wc = w & 3;
  // bijective XCD swizzle (gridDim.x % 8 == 0)
  int nwg = (int)gridDim.x, bid = (int)blockIdx.x;
  int wg = (bid & 7)*(nwg>>3) + (bid>>3);
  int by = wg / nbx, bx = wg - by*nbx;
  int bm = by*256, bn = bx*256;
  int NT = K >> 6, NP = NT >> 1;
  f32x4 acc[8][4] = {};
  bf16x8 a_[4][2], b0_[2][2], b1_[2][2];
  // prologue: tile0 (A0,B0,B1,A1) then tile1 (A0,B0,B1,A1) -- 16 loads/wave
  stA8(A,lda,As0,bm,0,0,w,lane);
  stB8(B,ldb,Bs0,bn,0,0,w,lane);
  stB8(B,ldb,Bs0,bn,0,1,w,lane);
  stA8(A,lda,As0,bm,0,1,w,lane);
  stA8(A,lda,As1,bm,1,0,w,lane);
  stB8(B,ldb,Bs1,bn,1,0,w,lane);
  stB8(B,ldb,Bs1,bn,1,1,w,lane);
  stA8(A,lda,As1,bm,1,1,w,lane);
  VM8;                                   // tile0 landed, tile1 in flight
  BAR;
  for (int i=0;i<NP;i++){
    int t2 = 2*i+2; if (t2>NT-1) t2=NT-1;   // clamped garbage-stage on last iter
    int t3 = 2*i+3; if (t3>NT-1) t3=NT-1;
    // ---- ph1: read A0,B0(cur) -> MFMA (0,0) ----
    RDB8(Bs0,0,b0_);
    RDA8(As0,0);
    LGKM0; BAR;
    MMRUN(0,0,b0_);
    // ---- ph2: read B1(cur); stage A0,B0(t2) -> MFMA (0,1) ----
    RDB8(Bs0,1,b1_);
    stA8(A,lda,As0,bm,t2,0,w,lane);
    stB8(B,ldb,Bs0,bn,t2,0,w,lane);
    LGKM0; BAR;
    MMRUN(0,1,b1_);
    // ---- ph3: read A1(cur); stage B1(t2) -> MFMA (1,1) ----
    RDA8(As0,1);
    stB8(B,ldb,Bs0,bn,t2,1,w,lane);
    LGKM0; BAR;
    MMRUN(1,1,b1_);
    // ---- ph4: stage A1(t2); vmcnt(8) (tile 2i+1 landed) -> MFMA (1,0) ----
    stA8(A,lda,As0,bm,t2,1,w,lane);
    VM8; BAR;
    MMRUN(1,0,b0_);
    // ---- ph5: read A0,B0(2i+1) -> MFMA (0,0) ----
    RDB8(Bs1,0,b0_);
    RDA8(As1,0);
    LGKM0; BAR;
    MMRUN(0,0,b0_);
    // ---- ph6: read B1; stage A0,B0(t3) -> MFMA (0,1) ----
    RDB8(Bs1,1,b1_);
    stA8(A,lda,As1,bm,t3,0,w,lane);
    stB8(B,ldb,Bs1,bn,t3,0,w,lane);
    LGKM0; BAR;
    MMRUN(0,1,b1_);
    // ---- ph7: read A1; stage B1(t3) -> MFMA (1,1) ----
    RDA8(As1,1);
    stB8(B,ldb,Bs1,bn,t3,1,w,lane);
    LGKM0; BAR;
    MMRUN(1,1,b1_);
    // ---- ph8: stage A1(t3); vmcnt(8) (tile 2i+2 landed) -> MFMA (1,0) ----
    stA8(A,lda,As1,bm,t3,1,w,lane);
    VM8; BAR;
    MMRUN(1,0,b0_);
  }
  asm volatile("s_waitcnt vmcnt(0)" ::: "memory");    // drain garbage stages
  #pragma unroll
  for (int mi=0;mi<8;mi++){
    int row0 = bm + wr*128 + mi*16 + quad*4;
    #pragma unroll
    for (int nj=0;nj<4;nj++){
      int col = bn + wc*64 + nj*16 + m16;
      #pragma unroll
      for (int r=0;r<4;r++)
        C[(size_t)(row0+r)*ldc + col] = f2b(acc[mi][nj][r]);
    }
  }
}

// ---------------- GAT attention-vector precompute ----------------
__global__ __launch_bounds__(256) void wsvec(const float* __restrict__ W,
    const float* __restrict__ as_, const float* __restrict__ ad_,
    float* __restrict__ ws, float* __restrict__ wd,
    int Kreal, int H, int C)
{
  int wv = blockIdx.x*4 + (threadIdx.x>>6);
  int lane = threadIdx.x & 63;
  int k = wv / H, h = wv - k*H;
  float ps=0.f, pd=0.f;
  if (k < Kreal){
    const float* wr = W + (size_t)k*((size_t)H*C) + (size_t)h*C;
    const float* ar = as_ + (size_t)h*C;
    const float* dr = ad_ + (size_t)h*C;
    for (int c=lane;c<C;c+=64){ float w=wr[c]; ps += w*ar[c]; pd += w*dr[c]; }
  }
  #pragma unroll
  for (int o=32;o;o>>=1){ ps += __shfl_down(ps,o); pd += __shfl_down(pd,o); }
  if (lane==0){ ws[k*H+h]=ps; wd[k*H+h]=pd; }
}
// GAT1 logits (Kp=80), writes alsd[n][16] = [als(8) | ald(8)]
__global__ __launch_bounds__(256) void alk(const float* __restrict__ X,
    const float* __restrict__ ws, const float* __restrict__ wd,
    float* __restrict__ alsd, int Kp)
{
  int n = blockIdx.x, tid = threadIdx.x;
  int hh = tid>>5, l32 = tid&31;
  const float* xr = X + (size_t)n*Kp;
  float ps=0.f, pd=0.f;
  for (int k=l32;k<Kp;k+=32){
    float xv = xr[k];
    ps += xv*ws[k*8+hh];
    pd += xv*wd[k*8+hh];
  }
  #pragma unroll
  for (int o=16;o;o>>=1){ ps += __shfl_down(ps,o,32); pd += __shfl_down(pd,o,32); }
  if (l32==0){ alsd[n*16+hh]=ps; alsd[n*16+8+hh]=pd; }
}

// ---------------- GAT1 aggregate-first gather (emits hi/lo) ----------------
__global__ __launch_bounds__(256) void gat1_gather(
    const float* __restrict__ xpad, const float* __restrict__ alsd,
    const int* __restrict__ off, const int* __restrict__ csr,
    u16* __restrict__ y1h, u16* __restrict__ y1l)
{
  int d = blockIdx.x, tid = threadIdx.x;
  int hh = tid>>5, l32 = tid&31;
  int e0 = off[d], e1 = off[d+1];
  __shared__ float mh[8], lih[8], adh[8];
  __shared__ float wl[32][8];
  __shared__ int sl[32];
  if (tid < 8){
    float ad = alsd[d*16+8+tid]; adh[tid]=ad;
    float m=-1e30f, l=0.f;
    for (int e=e0;e<e1;++e){
      float xv = alsd[csr[e]*16+tid] + ad;
      xv = xv>0.f?xv:0.2f*xv;
      if (xv>m){ l = l*__expf(m-xv)+1.f; m=xv; } else l += __expf(xv-m);
    }
    mh[tid]=m; lih[tid]=1.f/l;
  }
  __syncthreads();
  float acc0=0.f, acc1=0.f, acc2v=0.f;
  for (int cb=e0; cb<e1; cb+=32){
    int ce = min(32, e1-cb);
    if (tid < ce*8){
      int j = tid>>3, h2 = tid&7;
      int s = csr[cb+j];
      if (h2==0) sl[j]=s;
      float xv = alsd[s*16+h2] + adh[h2];
      xv = xv>0.f?xv:0.2f*xv;
      wl[j][h2] = __expf(xv-mh[h2])*lih[h2];
    }
    __syncthreads();
    for (int j=0;j<ce;++j){
      float w = wl[j][hh];
      const float* xr = xpad + (size_t)sl[j]*80;
      acc0 += w*xr[l32];
      acc1 += w*xr[l32+32];
      if (l32 < 16) acc2v += w*xr[l32+64];
    }
    __syncthreads();
  }
  size_t base = (size_t)d*640 + hh*80;
  u16 h_, l_;
  split_bf(acc0, h_, l_); y1h[base+l32]=h_;    y1l[base+l32]=l_;
  split_bf(acc1, h_, l_); y1h[base+l32+32]=h_; y1l[base+l32+32]=l_;
  if (l32<16){ split_bf(acc2v, h_, l_); y1h[base+l32+64]=h_; y1l[base+l32+64]=l_; }
}

// ---------------- all-head chunk aggregation (bf16 h, alsd layout) ----------------
template<int HPC, int C>
__global__ __launch_bounds__(256) void gat_aggN(
    const u16* __restrict__ h, const float* __restrict__ alsd,
    const int* __restrict__ off, const int* __restrict__ csr,
    float* __restrict__ accum, int head0)
{
  constexpr int V = C/256;
  int d = blockIdx.x, tid = threadIdx.x;
  int e0=off[d], e1=off[d+1];
  __shared__ float mh[HPC], lih[HPC], adh[HPC];
  __shared__ float wl[32][HPC];
  __shared__ int sl[32];
  if (tid < HPC){
    float ad = alsd[d*16 + 8 + head0 + tid]; adh[tid]=ad;
    float m=-1e30f,l=0.f;
    for (int e=e0;e<e1;++e){
      float xv = alsd[csr[e]*16 + head0 + tid]+ad;
      xv = xv>0.f?xv:0.2f*xv;
      if (xv>m){ l=l*__expf(m-xv)+1.f; m=xv; } else l+=__expf(xv-m);
    }
    mh[tid]=m; lih[tid]=1.f/l;
  }
  __syncthreads();
  float acc[HPC][V];
  #pragma unroll
  for (int a=0;a<HPC;a++)
    #pragma unroll
    for (int v=0;v<V;v++) acc[a][v]=0.f;
  int c0 = tid*V;
  for (int cb=e0;cb<e1;cb+=32){
    int ce = min(32, e1-cb);
    if (tid < ce*HPC){
      int j = tid/HPC, h2 = tid - j*HPC;
      int s = csr[cb+j];
      if (h2==0) sl[j]=s;
      float xv = alsd[s*16 + head0 + h2] + adh[h2];
      xv = xv>0.f?xv:0.2f*xv;
      wl[j][h2] = __expf(xv-mh[h2])*lih[h2];
    }
    __syncthreads();
    for (int j=0;j<ce;++j){
      const u16* hr = h + (size_t)sl[j]*(HPC*C);
      #pragma unroll
      for (int a=0;a<HPC;a++){
        float w = wl[j][a];
        if constexpr (V==4){
          uint2 u = *(const uint2*)(hr + a*C + c0);
          acc[a][0] += w*blo(u.x); acc[a][1] += w*bhi(u.x);
          acc[a][2] += w*blo(u.y); acc[a][3] += w*bhi(u.y);
        } else {
          u32 u = *(const u32*)(hr + a*C + c0);
          acc[a][0] += w*blo(u); acc[a][1] += w*bhi(u);
        }
      }
    }
    __syncthreads();
  }
  float* ar = accum + (size_t)d*C + c0;
  #pragma unroll
  for (int v=0;v<V;v++){
    float s2 = 0.f;
    #pragma unroll
    for (int a=0;a<HPC;a++) s2 += acc[a][v];
    ar[v] += s2;
  }
}
// x3 = relu(acc/8 + b[c])  (fp32 out, GAT3)
__global__ __launch_bounds__(256) void finishx(const float* __restrict__ accum,
    const float* __restrict__ bias, float* __restrict__ xo, int Cmask){
  int i = blockIdx.x*256 + threadIdx.x;
  int c = i & Cmask;
  xo[i] = fmaxf(accum[i]*0.125f + bias[c], 0.f);
}
// x2 = relu(acc/8 + b[c]) -> hi/lo only (GAT2)
__global__ __launch_bounds__(256) void finishx2(const float* __restrict__ accum,
    const float* __restrict__ bias,
    u16* __restrict__ xh, u16* __restrict__ xl, int Cmask){
  int i = blockIdx.x*256 + threadIdx.x;
  int c = i & Cmask;
  float v = fmaxf(accum[i]*0.125f + bias[c], 0.f);
  u16 h_, l_; split_bf(v, h_, l_);
  xh[i]=h_; xl[i]=l_;
}

// ---------------- pooled GCN aggregation ----------------
__global__ __launch_bounds__(256) void pool_gcn(const float* __restrict__ x3,
    const float* __restrict__ dis, const int* __restrict__ off, const int* __restrict__ csr,
    float* __restrict__ z)
{
  int g = blockIdx.x, tid = threadIdx.x;
  int c0 = tid*2;
  float a0=0.f, a1=0.f;
  for (int dd=0; dd<32; ++dd){
    int d = g*32+dd;
    int e0=off[d], e1=off[d+1];
    float b0=0.f, b1=0.f;
    for (int e=e0;e<e1;++e){
      int s = csr[e]; float ds = dis[s];
      const float* xr = x3 + (size_t)s*512 + c0;
      b0 += ds*xr[0]; b1 += ds*xr[1];
    }
    float dw = dis[d];
    a0 += dw*b0; a1 += dw*b1;
  }
  z[(size_t)g*512+c0]   = a0*(1.f/32.f);
  z[(size_t)g*512+c0+1] = a1*(1.f/32.f);
}

// ---------------- TransformerConv aggregation (bf16 qkvs, logit-cache) ----------------
__global__ __launch_bounds__(256) void tr_agg(
  const u16* __restrict__ qkvs, const int* __restrict__ off, const int* __restrict__ csr,
  float* __restrict__ xt)
{
  int d = blockIdx.x, tid = threadIdx.x;
  int wv = tid>>6, lane = tid&63;
  int e0=off[d], e1=off[d+1];
  __shared__ float osum[4][512];
  __shared__ float sp[4][64];
  float qf[8];
  { uint4 u = *(const uint4*)(qkvs + (size_t)d*6656 + wv*512 + lane*8);
    qf[0]=blo(u.x); qf[1]=bhi(u.x); qf[2]=blo(u.y); qf[3]=bhi(u.y);
    qf[4]=blo(u.z); qf[5]=bhi(u.z); qf[6]=blo(u.w); qf[7]=bhi(u.w); }
  const float scale = 0.04419417382415922f; // 1/sqrt(512)
  float m=-1e30f,l=0.f;
  for (int e=e0;e<e1;++e){
    int s = csr[e];
    uint4 u = *(const uint4*)(qkvs + (size_t)s*6656 + 2048 + wv*512 + lane*8);
    float p = qf[0]*blo(u.x)+qf[1]*bhi(u.x)+qf[2]*blo(u.y)+qf[3]*bhi(u.y)
            + qf[4]*blo(u.z)+qf[5]*bhi(u.z)+qf[6]*blo(u.w)+qf[7]*bhi(u.w);
    #pragma unroll
    for (int o=32;o;o>>=1) p += __shfl_xor(p,o);
    p *= scale;
    int idx = e-e0;
    if (lane==0 && idx<64) sp[wv][idx]=p;
    if (p>m){ l=l*__expf(m-p)+1.f; m=p; } else l+=__expf(p-m);
  }
  float li = (e1>e0)?1.f/l:0.f;
  float acc[8]={0.f,0.f,0.f,0.f,0.f,0.f,0.f,0.f};
  for (int e=e0;e<e1;++e){
    int s = csr[e];
    int idx = e-e0;
    float p;
    if (idx<64) p = sp[wv][idx];
    else {
      uint4 u = *(const uint4*)(qkvs + (size_t)s*6656 + 2048 + wv*512 + lane*8);
      p = qf[0]*blo(u.x)+qf[1]*bhi(u.x)+qf[2]*blo(u.y)+qf[3]*bhi(u.y)
        + qf[4]*blo(u.z)+qf[5]*bhi(u.z)+qf[6]*blo(u.w)+qf[7]*bhi(u.w);
      #pragma unroll
      for (int o=32;o;o>>=1) p += __shfl_xor(p,o);
      p *= scale;
    }
    float w = __expf(p - m)*li;
    uint4 u = *(const uint4*)(qkvs + (size_t)s*6656 + 4096 + wv*512 + lane*8);
    acc[0]+=w*blo(u.x); acc[1]+=w*bhi(u.x); acc[2]+=w*blo(u.y); acc[3]+=w*bhi(u.y);
    acc[4]+=w*blo(u.z); acc[5]+=w*bhi(u.z); acc[6]+=w*blo(u.w); acc[7]+=w*bhi(u.w);
  }
  #pragma unroll
  for (int j=0;j<8;j++) osum[wv][lane*8+j]=acc[j];
  __syncthreads();
  for (int c=tid;c<512;c+=256){
    u16 sk = qkvs[(size_t)d*6656 + 6144 + c];
    float o = (osum[0][c]+osum[1][c]+osum[2][c]+osum[3][c])*0.25f + blo((u32)sk);
    xt[(size_t)d*512+c] = fmaxf(o,0.f);
  }
}

// ---------------- bias concat for qkv GEMM ----------------
__global__ __launch_bounds__(256) void catb(const float* __restrict__ bq, const float* __restrict__ bk,
    const float* __restrict__ bv, const float* __restrict__ bs, float* __restrict__ o){
  int i = blockIdx.x*256 + threadIdx.x; if (i>=6656) return;
  float v;
  if (i<2048) v=bq[i]; else if (i<4096) v=bk[i-2048];
  else if (i<6144) v=bv[i-4096]; else v=bs[i-6144];
  o[i]=v;
}

// ---------------- fused head (bf16 [N,K] weights) ----------------
__device__ __forceinline__ float dotb(const u16* __restrict__ w, const float* __restrict__ s,
                                      int k0, int k1){
  float acc=0.f;
  #pragma unroll 4
  for (int k=k0;k<k1;k+=8){
    uint4 u = *(const uint4*)(w+k);
    float4 s0 = *(const float4*)(s+k);
    float4 s1 = *(const float4*)(s+k+4);
    acc += blo(u.x)*s0.x + bhi(u.x)*s0.y + blo(u.y)*s0.z + bhi(u.y)*s0.w
         + blo(u.z)*s1.x + bhi(u.z)*s1.y + blo(u.w)*s1.z + bhi(u.w)*s1.w;
  }
  return acc;
}
__global__ __launch_bounds__(256) void head_k(
  const float* __restrict__ z, const float* __restrict__ xt, const float* __restrict__ fp,
  const u16* __restrict__ gcnT, const float* __restrict__ gcn_b,
  const u16* __restrict__ fc1T, const float* __restrict__ fc1_b,
  const u16* __restrict__ fc2T, const float* __restrict__ fc2_b,
  const u16* __restrict__ b1T, const float* __restrict__ b1_b,
  const u16* __restrict__ b2T, const float* __restrict__ b2_b,
  const u16* __restrict__ b3T, const float* __restrict__ b3_b,
  const float* __restrict__ b4_w, const float* __restrict__ b4_b,
  float* __restrict__ out)
{
  int g = blockIdx.x, tid = threadIdx.x;
  __shared__ __align__(16) float xc[1024];
  __shared__ __align__(16) float sa[1504];
  __shared__ __align__(16) float sb[256];
  __shared__ __align__(16) float scm[256];
  for (int c=tid;c<512;c+=256) sa[c] = z[(size_t)g*512+c];
  __syncthreads();
  float vgcn = gcn_b[tid] + dotb(gcnT + (size_t)tid*512, sa, 0, 512);
  for (int c=tid;c<512;c+=256){
    float s=0.f;
    for (int i=0;i<32;i++) s += xt[(size_t)(g*32+i)*512 + c];
    xc[256+c] = s*(1.f/32.f);
  }
  xc[tid] = vgcn;
  __syncthreads();
  for (int c=tid;c<1496;c+=256) sa[c] = (c<1489) ? fp[(size_t)g*1489+c] : 0.f;
  __syncthreads();
  { int n = tid & 127, half = tid >> 7;
    sb[tid] = dotb(fc1T + (size_t)n*1496, sa, half?752:0, half?1496:752); }
  __syncthreads();
  if (tid<128) scm[tid] = fmaxf(sb[tid]+sb[tid+128]+fc1_b[tid], 0.f);
  __syncthreads();
  xc[768+tid] = fmaxf(fc2_b[tid] + dotb(fc2T + (size_t)tid*128, scm, 0, 128), 0.f);
  __syncthreads();
  sa[tid] = fmaxf(b1_b[tid] + dotb(b1T + (size_t)tid*1024, xc, 0, 1024), 0.f);
  __syncthreads();
  { int n = tid & 127, half = tid >> 7;
    sb[tid] = dotb(b2T + (size_t)n*256, sa, half*128, half*128+128); }
  __syncthreads();
  if (tid<128) scm[tid] = fmaxf(sb[tid]+sb[tid+128]+b2_b[tid], 0.f);
  __syncthreads();
  { int n = tid & 63, part = tid >> 6;
    sb[tid] = dotb(b3T + (size_t)n*128, scm, part*32, part*32+32); }
  __syncthreads();
  if (tid<64) sa[tid] = fmaxf(sb[tid]+sb[tid+64]+sb[tid+128]+sb[tid+192]+b3_b[tid], 0.f);
  __syncthreads();
  if (tid<64){
    float p = sa[tid]*b4_w[tid];
    #pragma unroll
    for (int o=32;o;o>>=1) p += __shfl_down(p,o);
    if (tid==0) out[g] = 1.f/(1.f+__expf(-(p + b4_b[0])));
  }
}

extern "C" void kernel_launch(void* const* d_in, const int* in_sizes, int n_in,
                              void* d_out, int out_size, void* d_ws, size_t ws_size,
                              hipStream_t stream)
{
  (void)in_sizes; (void)n_in; (void)out_size; (void)ws_size;
  const float* x     = (const float*)d_in[0];
  const float* fp    = (const float*)d_in[1];
  const int*   ei    = (const int*)d_in[2];
  const float* g1_w  = (const float*)d_in[4];
  const float* g1_as = (const float*)d_in[5];
  const float* g1_ad = (const float*)d_in[6];
  const float* g1_b  = (const float*)d_in[7];
  const float* g2_w  = (const float*)d_in[8];
  const float* g2_as = (const float*)d_in[9];
  const float* g2_ad = (const float*)d_in[10];
  const float* g2_b  = (const float*)d_in[11];
  const float* g3_w  = (const float*)d_in[12];
  const float* g3_as = (const float*)d_in[13];
  const float* g3_ad = (const float*)d_in[14];
  const float* g3_b  = (const float*)d_in[15];
  const float* gcn_w = (const float*)d_in[16];
  const float* gcn_b = (const float*)d_in[17];
  const float* t_wq  = (const float*)d_in[18];
  const float* t_wk  = (const float*)d_in[19];
  const float* t_wv  = (const float*)d_in[20];
  const float* t_bq  = (const float*)d_in[21];
  const float* t_bk  = (const float*)d_in[22];
  const float* t_bv  = (const float*)d_in[23];
  const float* t_ws  = (const float*)d_in[24];
  const float* t_bs  = (const float*)d_in[25];
  const float* fc1_w = (const float*)d_in[26];
  const float* fc1_b = (const float*)d_in[27];
  const float* fc2_w = (const float*)d_in[28];
  const float* fc2_b = (const float*)d_in[29];
  const float* b1_w  = (const float*)d_in[30];
  const float* b1_b  = (const float*)d_in[31];
  const float* b2_w  = (const float*)d_in[32];
  const float* b2_b  = (const float*)d_in[33];
  const float* b3_w  = (const float*)d_in[34];
  const float* b3_b  = (const float*)d_in[35];
  const float* b4_w  = (const float*)d_in[36];
  const float* b4_b  = (const float*)d_in[37];

  char* base = (char*)d_ws;
  size_t offb = 0;
  auto alloc = [&](size_t bytes)->void*{
    void* p = base + offb; offb = (offb + bytes + 255) & ~(size_t)255; return p;
  };
  int*   cnt   = (int*)alloc(16384*4);
  int*   off_g = (int*)alloc(4097*4);
  int*   off_t = (int*)alloc(4097*4);
  int*   csr_g = (int*)alloc(12288*4);
  int*   csr_t = (int*)alloc(8192*4);
  float* dis   = (float*)alloc(4096*4);
  float* xpad  = (float*)alloc((size_t)4096*80*4);
  u16*   xph   = (u16*)alloc((size_t)4096*96*2);
  float* alsd  = (float*)alloc((size_t)4096*16*4);
  float* wsv   = (float*)alloc((size_t)2048*8*4);
  float* wdv   = (float*)alloc((size_t)2048*8*4);
  u16*   wsTh  = (u16*)alloc((size_t)16*2048*2);
  u16*   wsTl  = (u16*)alloc((size_t)16*2048*2);
  float* zbuf  = (float*)alloc((size_t)128*512*4);
  float* cbias = (float*)alloc((size_t)6656*4);
  float* w1r   = (float*)alloc((size_t)640*2048*4);
  u16*   gcnT  = (u16*)alloc((size_t)256*512*2);
  u16*   fc1T  = (u16*)alloc((size_t)128*1496*2);
  u16*   fc2T  = (u16*)alloc((size_t)256*128*2);
  u16*   b1T   = (u16*)alloc((size_t)256*1024*2);
  u16*   b2T   = (u16*)alloc((size_t)128*256*2);
  u16*   b3T   = (u16*)alloc((size_t)64*128*2);
  char*  big   = (char*)alloc((size_t)140<<20);

  // ---- overlays (MB offsets in big) ----
  // GAT1
  u16*   y1h   = (u16*)  (big);                         // [0,5)
  u16*   y1l   = (u16*)  (big + ((size_t)5<<20));       // [5,10)
  u16*   w1rth = (u16*)  (big + ((size_t)10<<20));      // [10,13)
  u16*   x1h   = (u16*)  (big + ((size_t)16<<20));      // [16,32)
  u16*   x1l   = (u16*)  (big + ((size_t)32<<20));      // [32,48)
  // GAT2
  u16*   w2th  = (u16*)  (big + ((size_t)48<<20));      // [48,64)  [4096][2048] bf16
  u16*   h2    = (u16*)  (big + ((size_t)64<<20));      // [64,96)  [4096][4096] bf16
  float* acc2  = (float*)(big + ((size_t)96<<20));      // [96,112)
  u16*   x2h   = (u16*)  (big + ((size_t)112<<20));     // [112,120)
  u16*   x2l   = (u16*)  (big + ((size_t)120<<20));     // [120,128)
  // GAT3 (GAT1/x1 regions dead)
  u16*   w3th  = (u16*)  (big);                         // [0,8)   [4096][1024] bf16
  u16*   h3    = (u16*)  (big + ((size_t)8<<20));       // [8,40)  [4096][4096] bf16
  float* acc3  = (float*)(big + ((size_t)40<<20));      // [40,48)
  float* x3    = (float*)(big + ((size_t)48<<20));      // [48,56)
  // TR phase
  u16*   qkvTh = (u16*)  (big);                         // [0,2)   (w3th dead)
  u16*   qkvs  = (u16*)  (big + ((size_t)8<<20));       // [8,64)  bf16 [4096][6656]
  float* xt    = (float*)(big + ((size_t)64<<20));      // [64,72) (h2 dead)

  int* deg_g = cnt;       int* cur_g = cnt+4096;
  int* deg_t = cnt+8192;  int* cur_t = cnt+12288;

  // ---- graph prep ----
  zero_i<<<64,256,0,stream>>>(cnt, 16384);
  hist_k<<<48,256,0,stream>>>(ei, deg_g, deg_t);
  scan4096<<<1,1024,0,stream>>>(deg_g, off_g);
  scan4096<<<1,1024,0,stream>>>(deg_t, off_t);
  scatter_k<<<48,256,0,stream>>>(ei, off_g, cur_g, csr_g, off_t, cur_t, csr_t);
  mkdis<<<16,256,0,stream>>>(deg_g, dis);
  pad_x<<<4096,128,0,stream>>>(x, xpad, xph);
  repack_w1<<<5120,256,0,stream>>>(g1_w, w1r);
  // head weight transposes (bf16)
  tpd<<<dim3(8,16),256,0,stream>>>(gcn_w, 256, 0, 512, 512, gcnT);
  tpd<<<dim3(4,47),256,0,stream>>>(fc1_w, 128, 0, 1489, 1496, fc1T);
  tpd<<<dim3(8,4), 256,0,stream>>>(fc2_w, 256, 0, 128, 128, fc2T);
  tpd<<<dim3(8,32),256,0,stream>>>(b1_w,  256, 0, 1024, 1024, b1T);
  tpd<<<dim3(4,8), 256,0,stream>>>(b2_w,  128, 0, 256, 256, b2T);
  tpd<<<dim3(2,4), 256,0,stream>>>(b3_w,  64,  0, 128, 128, b3T);

  // ---- GAT1 (aggregate-first) ----
  wsvec<<<160,256,0,stream>>>(g1_w, g1_as, g1_ad, wsv, wdv, 78, 8, 2048);
  alk<<<4096,256,0,stream>>>(xpad, wsv, wdv, alsd, 80);
  gat1_gather<<<4096,256,0,stream>>>(xpad, alsd, off_g, csr_g, y1h, y1l);
  tpd<<<dim3(64,20),256,0,stream>>>(w1r, 2048, 0, 640, 640, w1rth);
  mgemm<5,1,float><<<dim3(16,32),256,0,stream>>>(y1h, y1l, 640, w1rth, 640,
                                         nullptr, 2048, 640, g1_b, 0.125f, x1h, x1l);

  // ---- GAT2 ----
  wsvec<<<4096,256,0,stream>>>(g2_w, g2_as, g2_ad, wsv, wdv, 2048, 8, 1024);
  mk_wsT<<<128,256,0,stream>>>(wsv, wdv, wsTh, wsTl, 2048);
  hipMemsetAsync(alsd, 0, (size_t)4096*16*4, stream);
  alk_mm<8><<<dim3(8,32),256,0,stream>>>(x1h, x1l, 2048, wsTh, wsTl, alsd, 2048);
  hipMemsetAsync(acc2, 0, (size_t)4096*1024*4, stream);
  for (int c=0;c<2;c++){
    tpd<<<dim3(128,64),256,0,stream>>>(g2_w, 8192, c*4096, 2048, 2048, w2th);
    mgemm8<<<256,512,0,stream>>>(x1h, 2048, w2th, 2048, h2, 4096, 2048, 16);
    gat_aggN<4,1024><<<4096,256,0,stream>>>(h2, alsd, off_g, csr_g, acc2, c*4);
  }
  finishx2<<<16384,256,0,stream>>>(acc2, g2_b, x2h, x2l, 1023);

  // ---- GAT3 ----
  wsvec<<<2048,256,0,stream>>>(g3_w, g3_as, g3_ad, wsv, wdv, 1024, 8, 512);
  mk_wsT<<<64,256,0,stream>>>(wsv, wdv, wsTh, wsTl, 1024);
  hipMemsetAsync(alsd, 0, (size_t)4096*16*4, stream);
  alk_mm<8><<<dim3(8,32),256,0,stream>>>(x2h, x2l, 1024, wsTh, wsTl, alsd, 1024);
  hipMemsetAsync(acc3, 0, (size_t)4096*512*4, stream);
  tpd<<<dim3(128,32),256,0,stream>>>(g3_w, 4096, 0, 1024, 1024, w3th);
  mgemm8<<<256,512,0,stream>>>(x2h, 1024, w3th, 1024, h3, 4096, 1024, 16);
  gat_aggN<8,512><<<4096,256,0,stream>>>(h3, alsd, off_g, csr_g, acc3, 0);
  finishx<<<8192,256,0,stream>>>(acc3, g3_b, x3, 511);
  pool_gcn<<<128,256,0,stream>>>(x3, dis, off_g, csr_g, zbuf);

  // ---- Transformer branch ----
  tpd<<<dim3(64,3),256,0,stream>>>(t_wq, 2048, 0, 78, 96, qkvTh);
  tpd<<<dim3(64,3),256,0,stream>>>(t_wk, 2048, 0, 78, 96, qkvTh + (size_t)2048*96);
  tpd<<<dim3(64,3),256,0,stream>>>(t_wv, 2048, 0, 78, 96, qkvTh + (size_t)4096*96);
  tpd<<<dim3(16,3),256,0,stream>>>(t_ws, 512,  0, 78, 96, qkvTh + (size_t)6144*96);
  catb<<<26,256,0,stream>>>(t_bq, t_bk, t_bv, t_bs, cbias);
  mgemm<1,0,u16><<<dim3(52,32),256,0,stream>>>(xph, nullptr, 96, qkvTh, 96,
                                         qkvs, 6656, 96, cbias, 0.f, nullptr, nullptr);
  tr_agg<<<4096,256,0,stream>>>(qkvs, off_t, csr_t, xt);

  // ---- fused head ----
  head_k<<<128,256,0,stream>>>(zbuf, xt, fp, gcnT, gcn_b,
                               fc1T, fc1_b, fc2T, fc2_b,
                               b1T, b1_b, b2T, b2_b, b3T, b3_b, b4_w, b4_b,
                               (float*)d_out);
}